// Round 2
// baseline (948.763 us; speedup 1.0000x reference)
//
#include <hip/hip_runtime.h>

#define B_ 8
#define N_ 1025
#define D_ 768
#define H_ 12
#define NP_ 1024
#define ROWS_ (B_*N_)        /* 8200 */
#define ROWS_PAD_ 8320       /* 65*128 */
#define QKVC_ 2304
#define SCALE_ 0.03608439182435161f  /* 768^-0.5 */
#define EPS_ 1e-5f

typedef float f32x4 __attribute__((ext_vector_type(4)));
typedef short s16x8 __attribute__((ext_vector_type(8)));

__device__ __forceinline__ float blo(unsigned int u){
  union { unsigned int i; float f; } v; v.i = u << 16; return v.f;
}
__device__ __forceinline__ float bhi(unsigned int u){
  union { unsigned int i; float f; } v; v.i = u & 0xffff0000u; return v.f;
}
__device__ __forceinline__ float bf2f(unsigned short u){
  union { unsigned int i; float f; } v; v.i = ((unsigned int)u) << 16; return v.f;
}
__device__ __forceinline__ unsigned short f2bf(float f){
  union { unsigned int i; float f; } v; v.f = f;
  unsigned int b = v.i;
  b = b + 0x7fffu + ((b >> 16) & 1u);
  return (unsigned short)(b >> 16);
}

// ---------------- transpose (K x N) fp32 -> (N x K) bf16 ----------------
__global__ __launch_bounds__(256) void transpose_f2b(
    const float* __restrict__ src, unsigned short* __restrict__ dst,
    int K, int N) {
  __shared__ unsigned short tile[32][33];
  int kb = blockIdx.y * 32, nb = blockIdx.x * 32;
  int tx = threadIdx.x & 31, ty = threadIdx.x >> 5;  // 32 x 8
  #pragma unroll
  for (int i = 0; i < 4; i++) {
    int r = ty + i * 8;
    tile[r][tx] = f2bf(src[(size_t)(kb + r) * N + nb + tx]);
  }
  __syncthreads();
  #pragma unroll
  for (int i = 0; i < 4; i++) {
    int r = ty + i * 8;
    dst[(size_t)(nb + r) * K + kb + tx] = tile[tx][r];
  }
}

// ---------------- layernorm: x[8200][768] fp32 -> xn bf16 ----------------
__global__ __launch_bounds__(256) void layernorm_k(
    const float* __restrict__ x, const float* __restrict__ w,
    const float* __restrict__ b, unsigned short* __restrict__ xn) {
  int row = blockIdx.x;
  int t = threadIdx.x;
  const float* xr = x + (size_t)row * D_;
  float v0 = xr[t], v1 = xr[t + 256], v2 = xr[t + 512];
  __shared__ float rs[256], rq[256];
  rs[t] = v0 + v1 + v2;
  rq[t] = v0 * v0 + v1 * v1 + v2 * v2;
  __syncthreads();
  for (int st = 128; st > 0; st >>= 1) {
    if (t < st) { rs[t] += rs[t + st]; rq[t] += rq[t + st]; }
    __syncthreads();
  }
  float mean = rs[0] * (1.0f / 768.0f);
  float var = rq[0] * (1.0f / 768.0f) - mean * mean;
  var = var < 0.f ? 0.f : var;
  float rstd = rsqrtf(var + EPS_);
  unsigned short* yr = xn + (size_t)row * D_;
  yr[t]       = f2bf((v0 - mean) * rstd * w[t]       + b[t]);
  yr[t + 256] = f2bf((v1 - mean) * rstd * w[t + 256] + b[t + 256]);
  yr[t + 512] = f2bf((v2 - mean) * rstd * w[t + 512] + b[t + 512]);
}

// ---------------- GEMM: C[M][N] = A[M][K] * Bt[N][K]^T (+bias)
// bf16 in, fp32 acc; output bf16 (OF32=false) or fp32+bias (OF32=true).
// 128x128 block tile, BK=32, 4 waves in 2x2, 16x16x32 MFMA.
template <bool OF32>
__global__ __launch_bounds__(256) void gemm_bt(
    const unsigned short* __restrict__ A, const unsigned short* __restrict__ Bt,
    void* __restrict__ Cv, const float* __restrict__ bias,
    int Mvalid, int Nn, int Kk) {
  __shared__ short As[128 * 40];  // stride 40 bf16: b128-aligned rows, uniform banks
  __shared__ short Bs[128 * 40];
  int t = threadIdx.x;
  int bm = blockIdx.y * 128, bn = blockIdx.x * 128;
  int lane = t & 63, wave = t >> 6;
  int wm = (wave & 1) * 64, wn = (wave >> 1) * 64;
  int m16 = lane & 15, quad = lane >> 4;
  f32x4 acc[4][4];
  #pragma unroll
  for (int i = 0; i < 4; i++)
    #pragma unroll
    for (int j = 0; j < 4; j++) acc[i][j] = (f32x4){0.f, 0.f, 0.f, 0.f};

  int srow = t >> 1;               // 0..127
  int schunk = (t & 1) * 16;       // 0 or 16 (elements)
  int ksteps = Kk >> 5;
  for (int kt = 0; kt < ksteps; kt++) {
    __syncthreads();
    {
      const uint4* gp = (const uint4*)(A + (size_t)(bm + srow) * Kk + kt * 32 + schunk);
      uint4 a0 = gp[0], a1 = gp[1];
      *(uint4*)(&As[srow * 40 + schunk])     = a0;
      *(uint4*)(&As[srow * 40 + schunk + 8]) = a1;
      const uint4* gq = (const uint4*)(Bt + (size_t)(bn + srow) * Kk + kt * 32 + schunk);
      uint4 b0 = gq[0], b1 = gq[1];
      *(uint4*)(&Bs[srow * 40 + schunk])     = b0;
      *(uint4*)(&Bs[srow * 40 + schunk + 8]) = b1;
    }
    __syncthreads();
    s16x8 af[4], bfr[4];
    #pragma unroll
    for (int i = 0; i < 4; i++) {
      af[i]  = *(const s16x8*)(&As[(wm + i * 16 + m16) * 40 + quad * 8]);
      bfr[i] = *(const s16x8*)(&Bs[(wn + i * 16 + m16) * 40 + quad * 8]);
    }
    #pragma unroll
    for (int i = 0; i < 4; i++)
      #pragma unroll
      for (int j = 0; j < 4; j++)
        acc[i][j] = __builtin_amdgcn_mfma_f32_16x16x32_bf16(af[i], bfr[j], acc[i][j], 0, 0, 0);
  }
  // epilogue: C/D layout col=lane&15, row=quad*4+reg (verified m89/m91)
  #pragma unroll
  for (int j = 0; j < 4; j++) {
    int col = bn + wn + j * 16 + m16;
    float bv = bias ? bias[col] : 0.f;
    #pragma unroll
    for (int i = 0; i < 4; i++) {
      #pragma unroll
      for (int r = 0; r < 4; r++) {
        int row = bm + wm + i * 16 + quad * 4 + r;
        if (row < Mvalid) {
          if (OF32) ((float*)Cv)[(size_t)row * Nn + col] = acc[i][j][r] + bv;
          else ((unsigned short*)Cv)[(size_t)row * Nn + col] = f2bf(acc[i][j][r] + bv);
        }
      }
    }
  }
}

// ---------------- block-wide sum helper ----------------
__device__ __forceinline__ float block_sum(float v, float* red) {
  int t = threadIdx.x;
  red[t] = v;
  __syncthreads();
  for (int st = 128; st > 0; st >>= 1) {
    if (t < st) red[t] += red[t + st];
    __syncthreads();
  }
  float r = red[0];
  __syncthreads();
  return r;
}

// ---------------- CLS-row attention (row 0 of each (b,h)) ----------------
__global__ __launch_bounds__(256) void attn_cls(
    const unsigned short* __restrict__ qkv, const float* __restrict__ canny,
    const float* __restrict__ noise, unsigned short* __restrict__ attn_out) {
  int bh = blockIdx.x;
  int b = bh / H_, h = bh % H_;
  int t = threadIdx.x;
  __shared__ float s[N_];
  __shared__ float red[256];
  __shared__ float q[64];

  if (t < 64) q[t] = bf2f(qkv[(size_t)(b * N_) * QKVC_ + h * 64 + t]);
  __syncthreads();

  // logits of CLS row over all 1025 keys (scaled). exp-safe without max-sub.
  for (int j = t; j < N_; j += 256) {
    const unsigned short* krow = qkv + (size_t)(b * N_ + j) * QKVC_ + D_ + h * 64;
    float dot = 0.f;
    #pragma unroll
    for (int c = 0; c < 8; c++) {
      uint4 kk = *(const uint4*)(krow + c * 8);
      dot += q[c*8+0]*blo(kk.x) + q[c*8+1]*bhi(kk.x)
           + q[c*8+2]*blo(kk.y) + q[c*8+3]*bhi(kk.y)
           + q[c*8+4]*blo(kk.z) + q[c*8+5]*bhi(kk.z)
           + q[c*8+6]*blo(kk.w) + q[c*8+7]*bhi(kk.w);
    }
    s[j] = dot * SCALE_;
  }
  // canny/noise normalizers
  float cp = 0.f, npp = 0.f;
  for (int j = t; j < NP_; j += 256) {
    cp  += canny[b * NP_ + j] + 1.0f;
    npp += noise[b * NP_ + j];
  }
  float csum = block_sum(cp, red);
  float nsum = block_sum(npp, red);
  // first softmax over patch keys only (j>=1)
  float e1 = 0.f;
  for (int j = t; j < N_; j += 256) if (j >= 1) e1 += __expf(s[j]);
  float sum1 = block_sum(e1, red);
  // inject priors
  for (int j = t; j < N_; j += 256) {
    if (j >= 1) {
      s[j] = __expf(s[j]) / sum1
           + (canny[b * NP_ + j - 1] + 1.0f) / csum
           + noise[b * NP_ + j - 1] / nsum;
    }
  }
  __syncthreads();
  // second (full) softmax
  float e2 = 0.f;
  for (int j = t; j < N_; j += 256) { float e = __expf(s[j]); s[j] = e; e2 += e; }
  float sum2 = block_sum(e2, red);
  // PV
  int d = t & 63, g = t >> 6;
  float a = 0.f;
  for (int j = g; j < N_; j += 4)
    a += s[j] * bf2f(qkv[(size_t)(b * N_ + j) * QKVC_ + 2 * D_ + h * 64 + d]);
  red[t] = a;
  __syncthreads();
  if (t < 64) {
    float o = (red[t] + red[t + 64] + red[t + 128] + red[t + 192]) / sum2;
    attn_out[(size_t)(b * N_) * D_ + h * 64 + t] = f2bf(o);
  }
}

// ---------------- main attention: rows 1..1024, TQ=16 rows/block ----------------
__global__ __launch_bounds__(256) void attn_main(
    const unsigned short* __restrict__ qkv, unsigned short* __restrict__ attn_out) {
  int tile = blockIdx.x;  // 0..63
  int h = blockIdx.y;     // 0..11
  int b = blockIdx.z;     // 0..7
  int t = threadIdx.x;
  __shared__ float qs[16 * 64];
  __shared__ float ks[64 * 68];
  __shared__ float vs[64 * 68];
  __shared__ float ss[64 * 20];    // p[jj][r], stride 20 for 16B-aligned float4
  __shared__ float lred[256 * 4];
  __shared__ float lsum[16];

  // stage Q tile (fp32)
  {
    int r = t >> 4, c = (t & 15) * 4;
    int grow = b * N_ + 1 + tile * 16 + r;
    uint2 u = *(const uint2*)(qkv + (size_t)grow * QKVC_ + h * 64 + c);
    qs[r * 64 + c + 0] = blo(u.x);
    qs[r * 64 + c + 1] = bhi(u.x);
    qs[r * 64 + c + 2] = blo(u.y);
    qs[r * 64 + c + 3] = bhi(u.y);
  }
  int lane = t & 63;
  int rq = (t >> 6) * 4;  // this thread's 4 rows (both phases)
  float lp[4] = {0.f, 0.f, 0.f, 0.f};
  float oa[4] = {0.f, 0.f, 0.f, 0.f};
  int srow = t >> 2, sseg = (t & 3) * 16;  // staging: 64 rows x 4 segs of 16

  for (int jt = 0; jt < 17; jt++) {
    __syncthreads();
    // stage K/V tile (bf16 -> fp32 LDS), zero-pad j >= 1025
    {
      int j = jt * 64 + srow;
      float* kd = &ks[srow * 68 + sseg];
      float* vd = &vs[srow * 68 + sseg];
      if (j < N_) {
        const unsigned short* kp = qkv + (size_t)(b * N_ + j) * QKVC_ + D_ + h * 64 + sseg;
        uint4 k0 = *(const uint4*)kp, k1 = *(const uint4*)(kp + 8);
        uint4 v0 = *(const uint4*)(kp + D_), v1 = *(const uint4*)(kp + D_ + 8);
        kd[0]=blo(k0.x); kd[1]=bhi(k0.x); kd[2]=blo(k0.y); kd[3]=bhi(k0.y);
        kd[4]=blo(k0.z); kd[5]=bhi(k0.z); kd[6]=blo(k0.w); kd[7]=bhi(k0.w);
        kd[8]=blo(k1.x); kd[9]=bhi(k1.x); kd[10]=blo(k1.y); kd[11]=bhi(k1.y);
        kd[12]=blo(k1.z); kd[13]=bhi(k1.z); kd[14]=blo(k1.w); kd[15]=bhi(k1.w);
        vd[0]=blo(v0.x); vd[1]=bhi(v0.x); vd[2]=blo(v0.y); vd[3]=bhi(v0.y);
        vd[4]=blo(v0.z); vd[5]=bhi(v0.z); vd[6]=blo(v0.w); vd[7]=bhi(v0.w);
        vd[8]=blo(v1.x); vd[9]=bhi(v1.x); vd[10]=blo(v1.y); vd[11]=bhi(v1.y);
        vd[12]=blo(v1.z); vd[13]=bhi(v1.z); vd[14]=blo(v1.w); vd[15]=bhi(v1.w);
      } else {
        #pragma unroll
        for (int i = 0; i < 16; i++) { kd[i] = 0.f; vd[i] = 0.f; }
      }
    }
    __syncthreads();
    // QK: this thread computes rows rq..rq+3 at key jj (q reads wave-uniform=broadcast)
    {
      int j = jt * 64 + lane;
      float dt0 = 0.f, dt1 = 0.f, dt2 = 0.f, dt3 = 0.f;
      #pragma unroll
      for (int c = 0; c < 16; c++) {
        f32x4 kv = *(const f32x4*)(&ks[lane * 68 + c * 4]);
        f32x4 q0 = *(const f32x4*)(&qs[(rq + 0) * 64 + c * 4]);
        f32x4 q1 = *(const f32x4*)(&qs[(rq + 1) * 64 + c * 4]);
        f32x4 q2 = *(const f32x4*)(&qs[(rq + 2) * 64 + c * 4]);
        f32x4 q3 = *(const f32x4*)(&qs[(rq + 3) * 64 + c * 4]);
        dt0 += q0[0]*kv[0] + q0[1]*kv[1] + q0[2]*kv[2] + q0[3]*kv[3];
        dt1 += q1[0]*kv[0] + q1[1]*kv[1] + q1[2]*kv[2] + q1[3]*kv[3];
        dt2 += q2[0]*kv[0] + q2[1]*kv[1] + q2[2]*kv[2] + q2[3]*kv[3];
        dt3 += q3[0]*kv[0] + q3[1]*kv[1] + q3[2]*kv[2] + q3[3]*kv[3];
      }
      bool valid = (j < N_);
      float p0 = valid ? __expf(dt0 * SCALE_) : 0.f;
      float p1 = valid ? __expf(dt1 * SCALE_) : 0.f;
      float p2 = valid ? __expf(dt2 * SCALE_) : 0.f;
      float p3 = valid ? __expf(dt3 * SCALE_) : 0.f;
      lp[0] += p0; lp[1] += p1; lp[2] += p2; lp[3] += p3;
      *(f32x4*)(&ss[lane * 20 + rq]) = (f32x4){p0, p1, p2, p3};
    }
    __syncthreads();
    // PV: this thread owns dim d=lane for rows rq..rq+3, all 64 keys (p reads broadcast)
    for (int j2 = 0; j2 < 64; j2++) {
      float vv = vs[j2 * 68 + lane];
      f32x4 p4 = *(const f32x4*)(&ss[j2 * 20 + rq]);
      oa[0] += p4[0] * vv; oa[1] += p4[1] * vv;
      oa[2] += p4[2] * vv; oa[3] += p4[3] * vv;
    }
  }
  // reduce l across the 64 jj-threads of each wave
  *(f32x4*)(&lred[t * 4]) = (f32x4){lp[0], lp[1], lp[2], lp[3]};
  __syncthreads();
  if (t < 16) {
    float ssum = 0.f;
    for (int u = 0; u < 64; u++) ssum += lred[((t >> 2) * 64 + u) * 4 + (t & 3)];
    lsum[t] = ssum;
  }
  __syncthreads();
  #pragma unroll
  for (int i = 0; i < 4; i++) {
    int rl = rq + i;
    float val = oa[i] / lsum[rl];
    int grow = b * N_ + 1 + tile * 16 + rl;
    attn_out[(size_t)grow * D_ + h * 64 + lane] = f2bf(val);
  }
}

// ---------------- launch ----------------
extern "C" void kernel_launch(void* const* d_in, const int* in_sizes, int n_in,
                              void* d_out, int out_size, void* d_ws, size_t ws_size,
                              hipStream_t stream) {
  (void)in_sizes; (void)n_in; (void)out_size; (void)ws_size;
  const float* x     = (const float*)d_in[0];
  const float* canny = (const float*)d_in[1];
  const float* noise = (const float*)d_in[2];
  const float* lnw   = (const float*)d_in[3];
  const float* lnb   = (const float*)d_in[4];
  const float* wqkv  = (const float*)d_in[5];
  const float* wout  = (const float*)d_in[6];
  const float* bout  = (const float*)d_in[7];
  float* out = (float*)d_out;
  char* ws = (char*)d_ws;

  // ws layout (all 256B aligned):
  unsigned short* xn    = (unsigned short*)(ws);              // 8320*768 bf16 (reused as attn_out)
  unsigned short* wqkvT = (unsigned short*)(ws + 12779520);   // 2304*768
  unsigned short* woutT = (unsigned short*)(ws + 16318464);   // 768*768
  unsigned short* qkv   = (unsigned short*)(ws + 17498112);   // 8200*2304

  transpose_f2b<<<dim3(QKVC_ / 32, D_ / 32), 256, 0, stream>>>(wqkv, wqkvT, D_, QKVC_);
  transpose_f2b<<<dim3(D_ / 32, D_ / 32), 256, 0, stream>>>(wout, woutT, D_, D_);
  layernorm_k<<<dim3(ROWS_), 256, 0, stream>>>(x, lnw, lnb, xn);
  gemm_bt<false><<<dim3(QKVC_ / 128, ROWS_PAD_ / 128), 256, 0, stream>>>(
      xn, wqkvT, (void*)qkv, nullptr, ROWS_, QKVC_, D_);
  attn_cls<<<dim3(B_ * H_), 256, 0, stream>>>(qkv, canny, noise, xn);
  attn_main<<<dim3(64, H_, B_), 256, 0, stream>>>(qkv, xn);
  gemm_bt<true><<<dim3(D_ / 128, ROWS_PAD_ / 128), 256, 0, stream>>>(
      xn, woutT, (void*)out, bout, ROWS_, D_, D_);
}

// Round 3
// 335.092 us; speedup vs baseline: 2.8314x; 2.8314x over previous
//
#include <hip/hip_runtime.h>

#define B_ 8
#define N_ 1025
#define D_ 768
#define H_ 12
#define NP_ 1024
#define ROWS_ (B_*N_)        /* 8200 */
#define ROWS_PAD_ 8320       /* 65*128 */
#define QKVC_ 2304
#define SCALE_ 0.03608439182435161f  /* 768^-0.5 */
#define EPS_ 1e-5f

typedef float f32x4 __attribute__((ext_vector_type(4)));
typedef short s16x8 __attribute__((ext_vector_type(8)));
typedef unsigned short u16x4 __attribute__((ext_vector_type(4)));

__device__ __forceinline__ float bf2f(unsigned short u){
  union { unsigned int i; float f; } v; v.i = ((unsigned int)u) << 16; return v.f;
}
__device__ __forceinline__ unsigned short f2bf(float f){
  union { unsigned int i; float f; } v; v.f = f;
  unsigned int b = v.i;
  b = b + 0x7fffu + ((b >> 16) & 1u);
  return (unsigned short)(b >> 16);
}

// ---------------- transpose (K x N) fp32 -> (N x K) bf16 ----------------
__global__ __launch_bounds__(256) void transpose_f2b(
    const float* __restrict__ src, unsigned short* __restrict__ dst,
    int K, int N) {
  __shared__ unsigned short tile[32][33];
  int kb = blockIdx.y * 32, nb = blockIdx.x * 32;
  int tx = threadIdx.x & 31, ty = threadIdx.x >> 5;  // 32 x 8
  #pragma unroll
  for (int i = 0; i < 4; i++) {
    int r = ty + i * 8;
    tile[r][tx] = f2bf(src[(size_t)(kb + r) * N + nb + tx]);
  }
  __syncthreads();
  #pragma unroll
  for (int i = 0; i < 4; i++) {
    int r = ty + i * 8;
    dst[(size_t)(nb + r) * K + kb + tx] = tile[tx][r];
  }
}

// ---------------- layernorm: x[8200][768] fp32 -> xn bf16 ----------------
__global__ __launch_bounds__(256) void layernorm_k(
    const float* __restrict__ x, const float* __restrict__ w,
    const float* __restrict__ b, unsigned short* __restrict__ xn) {
  int row = blockIdx.x;
  int t = threadIdx.x;
  const float* xr = x + (size_t)row * D_;
  float v0 = xr[t], v1 = xr[t + 256], v2 = xr[t + 512];
  __shared__ float rs[256], rq[256];
  rs[t] = v0 + v1 + v2;
  rq[t] = v0 * v0 + v1 * v1 + v2 * v2;
  __syncthreads();
  for (int st = 128; st > 0; st >>= 1) {
    if (t < st) { rs[t] += rs[t + st]; rq[t] += rq[t + st]; }
    __syncthreads();
  }
  float mean = rs[0] * (1.0f / 768.0f);
  float var = rq[0] * (1.0f / 768.0f) - mean * mean;
  var = var < 0.f ? 0.f : var;
  float rstd = rsqrtf(var + EPS_);
  unsigned short* yr = xn + (size_t)row * D_;
  yr[t]       = f2bf((v0 - mean) * rstd * w[t]       + b[t]);
  yr[t + 256] = f2bf((v1 - mean) * rstd * w[t + 256] + b[t + 256]);
  yr[t + 512] = f2bf((v2 - mean) * rstd * w[t + 512] + b[t + 512]);
}

// ---------------- GEMM: C[M][N] = A[M][K] * Bt[N][K]^T (+bias)
// bf16 in, fp32 acc; output bf16 (OF32=false) or fp32+bias (OF32=true).
template <bool OF32>
__global__ __launch_bounds__(256) void gemm_bt(
    const unsigned short* __restrict__ A, const unsigned short* __restrict__ Bt,
    void* __restrict__ Cv, const float* __restrict__ bias,
    int Mvalid, int Nn, int Kk) {
  __shared__ short As[128 * 40];
  __shared__ short Bs[128 * 40];
  int t = threadIdx.x;
  int bm = blockIdx.y * 128, bn = blockIdx.x * 128;
  int lane = t & 63, wave = t >> 6;
  int wm = (wave & 1) * 64, wn = (wave >> 1) * 64;
  int m16 = lane & 15, quad = lane >> 4;
  f32x4 acc[4][4];
  #pragma unroll
  for (int i = 0; i < 4; i++)
    #pragma unroll
    for (int j = 0; j < 4; j++) acc[i][j] = (f32x4){0.f, 0.f, 0.f, 0.f};

  int srow = t >> 1;
  int schunk = (t & 1) * 16;
  int ksteps = Kk >> 5;
  for (int kt = 0; kt < ksteps; kt++) {
    __syncthreads();
    {
      const uint4* gp = (const uint4*)(A + (size_t)(bm + srow) * Kk + kt * 32 + schunk);
      uint4 a0 = gp[0], a1 = gp[1];
      *(uint4*)(&As[srow * 40 + schunk])     = a0;
      *(uint4*)(&As[srow * 40 + schunk + 8]) = a1;
      const uint4* gq = (const uint4*)(Bt + (size_t)(bn + srow) * Kk + kt * 32 + schunk);
      uint4 b0 = gq[0], b1 = gq[1];
      *(uint4*)(&Bs[srow * 40 + schunk])     = b0;
      *(uint4*)(&Bs[srow * 40 + schunk + 8]) = b1;
    }
    __syncthreads();
    s16x8 af[4], bfr[4];
    #pragma unroll
    for (int i = 0; i < 4; i++) {
      af[i]  = *(const s16x8*)(&As[(wm + i * 16 + m16) * 40 + quad * 8]);
      bfr[i] = *(const s16x8*)(&Bs[(wn + i * 16 + m16) * 40 + quad * 8]);
    }
    #pragma unroll
    for (int i = 0; i < 4; i++)
      #pragma unroll
      for (int j = 0; j < 4; j++)
        acc[i][j] = __builtin_amdgcn_mfma_f32_16x16x32_bf16(af[i], bfr[j], acc[i][j], 0, 0, 0);
  }
  #pragma unroll
  for (int j = 0; j < 4; j++) {
    int col = bn + wn + j * 16 + m16;
    float bv = bias ? bias[col] : 0.f;
    #pragma unroll
    for (int i = 0; i < 4; i++) {
      #pragma unroll
      for (int r = 0; r < 4; r++) {
        int row = bm + wm + i * 16 + quad * 4 + r;
        if (row < Mvalid) {
          if (OF32) ((float*)Cv)[(size_t)row * Nn + col] = acc[i][j][r] + bv;
          else ((unsigned short*)Cv)[(size_t)row * Nn + col] = f2bf(acc[i][j][r] + bv);
        }
      }
    }
  }
}

// ---------------- block-wide sum helper ----------------
__device__ __forceinline__ float block_sum(float v, float* red) {
  int t = threadIdx.x;
  red[t] = v;
  __syncthreads();
  for (int st = 128; st > 0; st >>= 1) {
    if (t < st) red[t] += red[t + st];
    __syncthreads();
  }
  float r = red[0];
  __syncthreads();
  return r;
}

// ---------------- CLS-row attention (row 0 of each (b,h)) ----------------
__global__ __launch_bounds__(256) void attn_cls(
    const unsigned short* __restrict__ qkv, const float* __restrict__ canny,
    const float* __restrict__ noise, unsigned short* __restrict__ attn_out) {
  int bh = blockIdx.x;
  int b = bh / H_, h = bh % H_;
  int t = threadIdx.x;
  __shared__ float s[N_];
  __shared__ float red[256];
  __shared__ float q[64];

  if (t < 64) q[t] = bf2f(qkv[(size_t)(b * N_) * QKVC_ + h * 64 + t]);
  __syncthreads();

  for (int j = t; j < N_; j += 256) {
    const unsigned short* krow = qkv + (size_t)(b * N_ + j) * QKVC_ + D_ + h * 64;
    float dot = 0.f;
    #pragma unroll
    for (int c = 0; c < 64; c++) dot += q[c] * bf2f(krow[c]);
    s[j] = dot * SCALE_;
  }
  float cp = 0.f, npp = 0.f;
  for (int j = t; j < NP_; j += 256) {
    cp  += canny[b * NP_ + j] + 1.0f;
    npp += noise[b * NP_ + j];
  }
  float csum = block_sum(cp, red);
  float nsum = block_sum(npp, red);
  float e1 = 0.f;
  for (int j = t; j < N_; j += 256) if (j >= 1) e1 += __expf(s[j]);
  float sum1 = block_sum(e1, red);
  for (int j = t; j < N_; j += 256) {
    if (j >= 1) {
      s[j] = __expf(s[j]) / sum1
           + (canny[b * NP_ + j - 1] + 1.0f) / csum
           + noise[b * NP_ + j - 1] / nsum;
    }
  }
  __syncthreads();
  float e2 = 0.f;
  for (int j = t; j < N_; j += 256) { float e = __expf(s[j]); s[j] = e; e2 += e; }
  float sum2 = block_sum(e2, red);
  int d = t & 63, g = t >> 6;
  float a = 0.f;
  for (int j = g; j < N_; j += 4)
    a += s[j] * bf2f(qkv[(size_t)(b * N_ + j) * QKVC_ + 2 * D_ + h * 64 + d]);
  red[t] = a;
  __syncthreads();
  if (t < 64) {
    float o = (red[t] + red[t + 64] + red[t + 128] + red[t + 192]) / sum2;
    attn_out[(size_t)(b * N_) * D_ + h * 64 + t] = f2bf(o);
  }
}

// ---------------- main attention (MFMA): rows 1..1024, 128 rows/block ----------------
// S^T = K·Q^T via mfma (A=K[key][hd], B=Q[row][hd]) so each lane holds P for a
// fixed q-row (col=lane&15) and 4 consecutive keys (row=quad*4+reg) -> b64 P
// writes to LDS in PV A-operand layout. V^T staged per tile for the PV B-operand.
__global__ __launch_bounds__(256) void attn_main(
    const unsigned short* __restrict__ qkv, unsigned short* __restrict__ attn_out) {
  int tile = blockIdx.x;  // 0..7 (128 q-rows each)
  int h = blockIdx.y;     // 0..11
  int b = blockIdx.z;     // 0..7
  int t = threadIdx.x;
  int lane = t & 63, w = t >> 6;
  int m16 = lane & 15, quad = lane >> 4;

  __shared__ short ps[128 * 72];        // Q staging, then P tiles [row][key]
  __shared__ short ks[64 * 72];         // K tile [key][hd]
  __shared__ unsigned int vs[64 * 36];  // V^T tile [dim][keypair]
  __shared__ float lsum[128];

  int qbase = 1 + tile * 128;

  // ---- stage Q (each wave stages exactly its own 32 rows: t>>1 in [32w,32w+31])
  {
    int r = t >> 1, seg = (t & 1) * 32;
    const uint4* src = (const uint4*)(qkv + (size_t)(b * N_ + qbase + r) * QKVC_ + h * 64 + seg);
    uint4 u0 = src[0], u1 = src[1], u2 = src[2], u3 = src[3];
    *(uint4*)(&ps[r * 72 + seg])      = u0;
    *(uint4*)(&ps[r * 72 + seg + 8])  = u1;
    *(uint4*)(&ps[r * 72 + seg + 16]) = u2;
    *(uint4*)(&ps[r * 72 + seg + 24]) = u3;
  }
  // ---- Q B-operand fragments (lane n=m16 -> q-row, k=hd quad*8+j), held in regs
  s16x8 qb[2][2];
  #pragma unroll
  for (int nt = 0; nt < 2; nt++)
    #pragma unroll
    for (int ks_ = 0; ks_ < 2; ks_++)
      qb[nt][ks_] = *(const s16x8*)(&ps[(w * 32 + nt * 16 + m16) * 72 + ks_ * 32 + quad * 8]);

  f32x4 oacc[2][4];
  #pragma unroll
  for (int mt = 0; mt < 2; mt++)
    #pragma unroll
    for (int dt = 0; dt < 4; dt++) oacc[mt][dt] = (f32x4){0.f, 0.f, 0.f, 0.f};
  float lp[2] = {0.f, 0.f};

  for (int jt = 0; jt < 17; jt++) {
    __syncthreads();  // prior QK(ks) + PV(vs) reads complete
    // ---- stage K tile [key][hd]
    {
      int key = t >> 2, seg = (t & 3) * 16;
      int j = jt * 64 + key;
      uint4 k0 = {0, 0, 0, 0}, k1 = {0, 0, 0, 0};
      if (j < N_) {
        const uint4* src = (const uint4*)(qkv + (size_t)(b * N_ + j) * QKVC_ + D_ + h * 64 + seg);
        k0 = src[0]; k1 = src[1];
      }
      *(uint4*)(&ks[key * 72 + seg])     = k0;
      *(uint4*)(&ks[key * 72 + seg + 8]) = k1;
    }
    // ---- stage V^T tile [dim][key] (packed keypairs)
    {
      int p2 = t & 31, seg = t >> 5;  // keypair, dim-segment(8 dims)
      int j0 = jt * 64 + 2 * p2, j1 = j0 + 1;
      uint4 va = {0, 0, 0, 0}, vb = {0, 0, 0, 0};
      if (j0 < N_) va = *(const uint4*)(qkv + (size_t)(b * N_ + j0) * QKVC_ + 2 * D_ + h * 64 + seg * 8);
      if (j1 < N_) vb = *(const uint4*)(qkv + (size_t)(b * N_ + j1) * QKVC_ + 2 * D_ + h * 64 + seg * 8);
      const unsigned short* pa_ = (const unsigned short*)&va;
      const unsigned short* pb_ = (const unsigned short*)&vb;
      #pragma unroll
      for (int i = 0; i < 8; i++)
        vs[(seg * 8 + i) * 36 + p2] = (unsigned int)pa_[i] | ((unsigned int)pb_[i] << 16);
    }
    __syncthreads();
    // ---- QK: S^T[key][qrow] per wave: 4 key-tiles x 2 row-tiles
    f32x4 sacc[4][2];
    #pragma unroll
    for (int kt = 0; kt < 4; kt++) {
      s16x8 ka0 = *(const s16x8*)(&ks[(kt * 16 + m16) * 72 + quad * 8]);
      s16x8 ka1 = *(const s16x8*)(&ks[(kt * 16 + m16) * 72 + 32 + quad * 8]);
      #pragma unroll
      for (int nt = 0; nt < 2; nt++) {
        f32x4 s = (f32x4){0.f, 0.f, 0.f, 0.f};
        s = __builtin_amdgcn_mfma_f32_16x16x32_bf16(ka0, qb[nt][0], s, 0, 0, 0);
        s = __builtin_amdgcn_mfma_f32_16x16x32_bf16(ka1, qb[nt][1], s, 0, 0, 0);
        sacc[kt][nt] = s;
      }
    }
    // ---- P = exp(S*scale), masked; pack 4 consecutive keys -> b64 write
    #pragma unroll
    for (int kt = 0; kt < 4; kt++) {
      int kb = jt * 64 + kt * 16 + quad * 4;
      #pragma unroll
      for (int nt = 0; nt < 2; nt++) {
        f32x4 s = sacc[kt][nt];
        float p0 = (kb + 0 < N_) ? __expf(s[0] * SCALE_) : 0.f;
        float p1 = (kb + 1 < N_) ? __expf(s[1] * SCALE_) : 0.f;
        float p2 = (kb + 2 < N_) ? __expf(s[2] * SCALE_) : 0.f;
        float p3 = (kb + 3 < N_) ? __expf(s[3] * SCALE_) : 0.f;
        lp[nt] += p0 + p1 + p2 + p3;
        u16x4 pk = {f2bf(p0), f2bf(p1), f2bf(p2), f2bf(p3)};
        *(u16x4*)(&ps[(w * 32 + nt * 16 + m16) * 72 + kt * 16 + quad * 4]) = pk;
      }
    }
    __syncthreads();
    // ---- PV: O[qrow][dim] += P·V
    s16x8 pa[2][2];
    #pragma unroll
    for (int mt = 0; mt < 2; mt++)
      #pragma unroll
      for (int ks_ = 0; ks_ < 2; ks_++)
        pa[mt][ks_] = *(const s16x8*)(&ps[(w * 32 + mt * 16 + m16) * 72 + ks_ * 32 + quad * 8]);
    const short* vss = (const short*)vs;
    #pragma unroll
    for (int dt = 0; dt < 4; dt++) {
      s16x8 vb0 = *(const s16x8*)(&vss[(dt * 16 + m16) * 72 + quad * 8]);
      s16x8 vb1 = *(const s16x8*)(&vss[(dt * 16 + m16) * 72 + 32 + quad * 8]);
      #pragma unroll
      for (int mt = 0; mt < 2; mt++) {
        oacc[mt][dt] = __builtin_amdgcn_mfma_f32_16x16x32_bf16(pa[mt][0], vb0, oacc[mt][dt], 0, 0, 0);
        oacc[mt][dt] = __builtin_amdgcn_mfma_f32_16x16x32_bf16(pa[mt][1], vb1, oacc[mt][dt], 0, 0, 0);
      }
    }
  }
  // ---- l: reduce across the 4 quad-lanes holding each q-row
  #pragma unroll
  for (int nt = 0; nt < 2; nt++) {
    float l = lp[nt];
    l += __shfl_xor(l, 16, 64);
    l += __shfl_xor(l, 32, 64);
    if (quad == 0) lsum[w * 32 + nt * 16 + m16] = l;
  }
  __syncthreads();
  // ---- normalize + store (O layout: row=quad*4+reg+mt*16, dim=dt*16+m16)
  #pragma unroll
  for (int mt = 0; mt < 2; mt++) {
    float rinv[4];
    #pragma unroll
    for (int r = 0; r < 4; r++) rinv[r] = 1.0f / lsum[w * 32 + mt * 16 + quad * 4 + r];
    #pragma unroll
    for (int dt = 0; dt < 4; dt++) {
      #pragma unroll
      for (int r = 0; r < 4; r++) {
        int grow = b * N_ + qbase + w * 32 + mt * 16 + quad * 4 + r;
        attn_out[(size_t)grow * D_ + h * 64 + dt * 16 + m16] = f2bf(oacc[mt][dt][r] * rinv[r]);
      }
    }
  }
}

// ---------------- launch ----------------
extern "C" void kernel_launch(void* const* d_in, const int* in_sizes, int n_in,
                              void* d_out, int out_size, void* d_ws, size_t ws_size,
                              hipStream_t stream) {
  (void)in_sizes; (void)n_in; (void)out_size; (void)ws_size;
  const float* x     = (const float*)d_in[0];
  const float* canny = (const float*)d_in[1];
  const float* noise = (const float*)d_in[2];
  const float* lnw   = (const float*)d_in[3];
  const float* lnb   = (const float*)d_in[4];
  const float* wqkv  = (const float*)d_in[5];
  const float* wout  = (const float*)d_in[6];
  const float* bout  = (const float*)d_in[7];
  float* out = (float*)d_out;
  char* ws = (char*)d_ws;

  unsigned short* xn    = (unsigned short*)(ws);              // 8320*768 bf16 (reused as attn_out)
  unsigned short* wqkvT = (unsigned short*)(ws + 12779520);   // 2304*768
  unsigned short* woutT = (unsigned short*)(ws + 16318464);   // 768*768
  unsigned short* qkv   = (unsigned short*)(ws + 17498112);   // 8200*2304

  transpose_f2b<<<dim3(QKVC_ / 32, D_ / 32), 256, 0, stream>>>(wqkv, wqkvT, D_, QKVC_);
  transpose_f2b<<<dim3(D_ / 32, D_ / 32), 256, 0, stream>>>(wout, woutT, D_, D_);
  layernorm_k<<<dim3(ROWS_), 256, 0, stream>>>(x, lnw, lnb, xn);
  gemm_bt<false><<<dim3(QKVC_ / 128, ROWS_PAD_ / 128), 256, 0, stream>>>(
      xn, wqkvT, (void*)qkv, nullptr, ROWS_, QKVC_, D_);
  attn_cls<<<dim3(B_ * H_), 256, 0, stream>>>(qkv, canny, noise, xn);
  attn_main<<<dim3(8, H_, B_), 256, 0, stream>>>(qkv, xn);
  gemm_bt<true><<<dim3(D_ / 128, ROWS_PAD_ / 128), 256, 0, stream>>>(
      xn, woutT, (void*)out, bout, ROWS_, D_, D_);
}

// Round 4
// 273.478 us; speedup vs baseline: 3.4693x; 1.2253x over previous
//
#include <hip/hip_runtime.h>

#define B_ 8
#define N_ 1025
#define D_ 768
#define H_ 12
#define NP_ 1024
#define ROWS_ (B_*N_)        /* 8200 */
#define ROWS_PAD_ 8320       /* 65*128 */
#define QKVC_ 2304
#define SCALE_ 0.03608439182435161f  /* 768^-0.5 */
#define EPS_ 1e-5f

typedef float f32x4 __attribute__((ext_vector_type(4)));
typedef short s16x8 __attribute__((ext_vector_type(8)));
typedef unsigned short u16x4 __attribute__((ext_vector_type(4)));

__device__ __forceinline__ float blo(unsigned int u){
  union { unsigned int i; float f; } v; v.i = u << 16; return v.f;
}
__device__ __forceinline__ float bhi(unsigned int u){
  union { unsigned int i; float f; } v; v.i = u & 0xffff0000u; return v.f;
}
__device__ __forceinline__ float bf2f(unsigned short u){
  union { unsigned int i; float f; } v; v.i = ((unsigned int)u) << 16; return v.f;
}
__device__ __forceinline__ unsigned short f2bf(float f){
  union { unsigned int i; float f; } v; v.f = f;
  unsigned int b = v.i;
  b = b + 0x7fffu + ((b >> 16) & 1u);
  return (unsigned short)(b >> 16);
}

// ---------------- transpose (K x N) fp32 -> (N x K) bf16 ----------------
__global__ __launch_bounds__(256) void transpose_f2b(
    const float* __restrict__ src, unsigned short* __restrict__ dst,
    int K, int N) {
  __shared__ unsigned short tile[32][33];
  int kb = blockIdx.y * 32, nb = blockIdx.x * 32;
  int tx = threadIdx.x & 31, ty = threadIdx.x >> 5;  // 32 x 8
  #pragma unroll
  for (int i = 0; i < 4; i++) {
    int r = ty + i * 8;
    tile[r][tx] = f2bf(src[(size_t)(kb + r) * N + nb + tx]);
  }
  __syncthreads();
  #pragma unroll
  for (int i = 0; i < 4; i++) {
    int r = ty + i * 8;
    dst[(size_t)(nb + r) * K + kb + tx] = tile[tx][r];
  }
}

// ---------------- layernorm: x[8200][768] fp32 -> xn bf16 ----------------
__global__ __launch_bounds__(256) void layernorm_k(
    const float* __restrict__ x, const float* __restrict__ w,
    const float* __restrict__ b, unsigned short* __restrict__ xn) {
  int row = blockIdx.x;
  int t = threadIdx.x;
  const float* xr = x + (size_t)row * D_;
  float v0 = xr[t], v1 = xr[t + 256], v2 = xr[t + 512];
  __shared__ float rs[256], rq[256];
  rs[t] = v0 + v1 + v2;
  rq[t] = v0 * v0 + v1 * v1 + v2 * v2;
  __syncthreads();
  for (int st = 128; st > 0; st >>= 1) {
    if (t < st) { rs[t] += rs[t + st]; rq[t] += rq[t + st]; }
    __syncthreads();
  }
  float mean = rs[0] * (1.0f / 768.0f);
  float var = rq[0] * (1.0f / 768.0f) - mean * mean;
  var = var < 0.f ? 0.f : var;
  float rstd = rsqrtf(var + EPS_);
  unsigned short* yr = xn + (size_t)row * D_;
  yr[t]       = f2bf((v0 - mean) * rstd * w[t]       + b[t]);
  yr[t + 256] = f2bf((v1 - mean) * rstd * w[t + 256] + b[t + 256]);
  yr[t + 512] = f2bf((v2 - mean) * rstd * w[t + 512] + b[t + 512]);
}

// ---------------- GEMM: C[M][N] = A[M][K] * Bt[N][K]^T (+bias)
// bf16 in, fp32 acc; output bf16 (OF32=false) or fp32+bias (OF32=true).
template <bool OF32>
__global__ __launch_bounds__(256) void gemm_bt(
    const unsigned short* __restrict__ A, const unsigned short* __restrict__ Bt,
    void* __restrict__ Cv, const float* __restrict__ bias,
    int Mvalid, int Nn, int Kk) {
  __shared__ short As[128 * 40];
  __shared__ short Bs[128 * 40];
  int t = threadIdx.x;
  int bm = blockIdx.y * 128, bn = blockIdx.x * 128;
  int lane = t & 63, wave = t >> 6;
  int wm = (wave & 1) * 64, wn = (wave >> 1) * 64;
  int m16 = lane & 15, quad = lane >> 4;
  f32x4 acc[4][4];
  #pragma unroll
  for (int i = 0; i < 4; i++)
    #pragma unroll
    for (int j = 0; j < 4; j++) acc[i][j] = (f32x4){0.f, 0.f, 0.f, 0.f};

  int srow = t >> 1;
  int schunk = (t & 1) * 16;
  int ksteps = Kk >> 5;
  for (int kt = 0; kt < ksteps; kt++) {
    __syncthreads();
    {
      const uint4* gp = (const uint4*)(A + (size_t)(bm + srow) * Kk + kt * 32 + schunk);
      uint4 a0 = gp[0], a1 = gp[1];
      *(uint4*)(&As[srow * 40 + schunk])     = a0;
      *(uint4*)(&As[srow * 40 + schunk + 8]) = a1;
      const uint4* gq = (const uint4*)(Bt + (size_t)(bn + srow) * Kk + kt * 32 + schunk);
      uint4 b0 = gq[0], b1 = gq[1];
      *(uint4*)(&Bs[srow * 40 + schunk])     = b0;
      *(uint4*)(&Bs[srow * 40 + schunk + 8]) = b1;
    }
    __syncthreads();
    s16x8 af[4], bfr[4];
    #pragma unroll
    for (int i = 0; i < 4; i++) {
      af[i]  = *(const s16x8*)(&As[(wm + i * 16 + m16) * 40 + quad * 8]);
      bfr[i] = *(const s16x8*)(&Bs[(wn + i * 16 + m16) * 40 + quad * 8]);
    }
    #pragma unroll
    for (int i = 0; i < 4; i++)
      #pragma unroll
      for (int j = 0; j < 4; j++)
        acc[i][j] = __builtin_amdgcn_mfma_f32_16x16x32_bf16(af[i], bfr[j], acc[i][j], 0, 0, 0);
  }
  #pragma unroll
  for (int j = 0; j < 4; j++) {
    int col = bn + wn + j * 16 + m16;
    float bv = bias ? bias[col] : 0.f;
    #pragma unroll
    for (int i = 0; i < 4; i++) {
      #pragma unroll
      for (int r = 0; r < 4; r++) {
        int row = bm + wm + i * 16 + quad * 4 + r;
        if (row < Mvalid) {
          if (OF32) ((float*)Cv)[(size_t)row * Nn + col] = acc[i][j][r] + bv;
          else ((unsigned short*)Cv)[(size_t)row * Nn + col] = f2bf(acc[i][j][r] + bv);
        }
      }
    }
  }
}

// ---------------- block-wide sum helper ----------------
__device__ __forceinline__ float block_sum(float v, float* red) {
  int t = threadIdx.x;
  red[t] = v;
  __syncthreads();
  for (int st = 128; st > 0; st >>= 1) {
    if (t < st) red[t] += red[t + st];
    __syncthreads();
  }
  float r = red[0];
  __syncthreads();
  return r;
}

// ---------------- CLS-row attention (row 0 of each (b,h)) ----------------
__global__ __launch_bounds__(256) void attn_cls(
    const unsigned short* __restrict__ qkv, const float* __restrict__ canny,
    const float* __restrict__ noise, unsigned short* __restrict__ attn_out) {
  int bh = blockIdx.x;
  int b = bh / H_, h = bh % H_;
  int t = threadIdx.x;
  __shared__ float s[N_];
  __shared__ float red[256];
  __shared__ float q[64];
  __shared__ float pvred[64 * 33];  // [dim][group], +1 pad -> conflict-free

  if (t < 64) q[t] = bf2f(qkv[(size_t)(b * N_) * QKVC_ + h * 64 + t]);
  __syncthreads();

  // QK: vectorized uint4 loads (8 x 16B per key row)
  for (int j = t; j < N_; j += 256) {
    const unsigned short* krow = qkv + (size_t)(b * N_ + j) * QKVC_ + D_ + h * 64;
    float dot = 0.f;
    #pragma unroll
    for (int c = 0; c < 8; c++) {
      uint4 kk = *(const uint4*)(krow + c * 8);
      dot += q[c*8+0]*blo(kk.x) + q[c*8+1]*bhi(kk.x)
           + q[c*8+2]*blo(kk.y) + q[c*8+3]*bhi(kk.y)
           + q[c*8+4]*blo(kk.z) + q[c*8+5]*bhi(kk.z)
           + q[c*8+6]*blo(kk.w) + q[c*8+7]*bhi(kk.w);
    }
    s[j] = dot * SCALE_;
  }
  float cp = 0.f, npp = 0.f;
  for (int j = t; j < NP_; j += 256) {
    cp  += canny[b * NP_ + j] + 1.0f;
    npp += noise[b * NP_ + j];
  }
  float csum = block_sum(cp, red);
  float nsum = block_sum(npp, red);
  float e1 = 0.f;
  for (int j = t; j < N_; j += 256) if (j >= 1) e1 += __expf(s[j]);
  float sum1 = block_sum(e1, red);
  for (int j = t; j < N_; j += 256) {
    if (j >= 1) {
      s[j] = __expf(s[j]) / sum1
           + (canny[b * NP_ + j - 1] + 1.0f) / csum
           + noise[b * NP_ + j - 1] / nsum;
    }
  }
  __syncthreads();
  float e2 = 0.f;
  for (int j = t; j < N_; j += 256) { float e = __expf(s[j]); s[j] = e; e2 += e; }
  float sum2 = block_sum(e2, red);
  // PV: thread owns dim-octet o (8 dims), strides 32 rows -> 1 uint4 load/iter
  {
    int o = t & 7, g = t >> 3;
    float a[8] = {0.f, 0.f, 0.f, 0.f, 0.f, 0.f, 0.f, 0.f};
    for (int j = g; j < N_; j += 32) {
      float sv = s[j];
      uint4 vv = *(const uint4*)(qkv + (size_t)(b * N_ + j) * QKVC_ + 2 * D_ + h * 64 + o * 8);
      a[0] += sv * blo(vv.x); a[1] += sv * bhi(vv.x);
      a[2] += sv * blo(vv.y); a[3] += sv * bhi(vv.y);
      a[4] += sv * blo(vv.z); a[5] += sv * bhi(vv.z);
      a[6] += sv * blo(vv.w); a[7] += sv * bhi(vv.w);
    }
    #pragma unroll
    for (int i = 0; i < 8; i++) pvred[(o * 8 + i) * 33 + g] = a[i];
  }
  __syncthreads();
  if (t < 64) {
    float acc = 0.f;
    #pragma unroll
    for (int u = 0; u < 32; u++) acc += pvred[t * 33 + u];
    attn_out[(size_t)(b * N_) * D_ + h * 64 + t] = f2bf(acc / sum2);
  }
}

// ---------------- main attention (MFMA): rows 1..1024, 128 rows/block ----------------
// S^T = K·Q^T via mfma (A=K[key][hd], B=Q[row][hd]) so each lane holds P for a
// fixed q-row (col=lane&15) and 4 consecutive keys (row=quad*4+reg) -> b64 P
// writes to LDS in PV A-operand layout. V^T staged per tile for the PV B-operand.
__global__ __launch_bounds__(256) void attn_main(
    const unsigned short* __restrict__ qkv, unsigned short* __restrict__ attn_out) {
  int tile = blockIdx.x;  // 0..7 (128 q-rows each)
  int h = blockIdx.y;     // 0..11
  int b = blockIdx.z;     // 0..7
  int t = threadIdx.x;
  int lane = t & 63, w = t >> 6;
  int m16 = lane & 15, quad = lane >> 4;

  __shared__ short ps[128 * 72];        // Q staging, then P tiles [row][key]
  __shared__ short ks[64 * 72];         // K tile [key][hd]
  __shared__ unsigned int vs[64 * 36];  // V^T tile [dim][keypair]
  __shared__ float lsum[128];

  int qbase = 1 + tile * 128;

  // ---- stage Q (each wave stages exactly its own 32 rows: t>>1 in [32w,32w+31])
  {
    int r = t >> 1, seg = (t & 1) * 32;
    const uint4* src = (const uint4*)(qkv + (size_t)(b * N_ + qbase + r) * QKVC_ + h * 64 + seg);
    uint4 u0 = src[0], u1 = src[1], u2 = src[2], u3 = src[3];
    *(uint4*)(&ps[r * 72 + seg])      = u0;
    *(uint4*)(&ps[r * 72 + seg + 8])  = u1;
    *(uint4*)(&ps[r * 72 + seg + 16]) = u2;
    *(uint4*)(&ps[r * 72 + seg + 24]) = u3;
  }
  // ---- Q B-operand fragments (lane n=m16 -> q-row, k=hd quad*8+j), held in regs
  s16x8 qb[2][2];
  #pragma unroll
  for (int nt = 0; nt < 2; nt++)
    #pragma unroll
    for (int ks_ = 0; ks_ < 2; ks_++)
      qb[nt][ks_] = *(const s16x8*)(&ps[(w * 32 + nt * 16 + m16) * 72 + ks_ * 32 + quad * 8]);

  f32x4 oacc[2][4];
  #pragma unroll
  for (int mt = 0; mt < 2; mt++)
    #pragma unroll
    for (int dt = 0; dt < 4; dt++) oacc[mt][dt] = (f32x4){0.f, 0.f, 0.f, 0.f};
  float lp[2] = {0.f, 0.f};

  for (int jt = 0; jt < 17; jt++) {
    __syncthreads();  // prior QK(ks) + PV(vs) reads complete
    // ---- stage K tile [key][hd]
    {
      int key = t >> 2, seg = (t & 3) * 16;
      int j = jt * 64 + key;
      uint4 k0 = {0, 0, 0, 0}, k1 = {0, 0, 0, 0};
      if (j < N_) {
        const uint4* src = (const uint4*)(qkv + (size_t)(b * N_ + j) * QKVC_ + D_ + h * 64 + seg);
        k0 = src[0]; k1 = src[1];
      }
      *(uint4*)(&ks[key * 72 + seg])     = k0;
      *(uint4*)(&ks[key * 72 + seg + 8]) = k1;
    }
    // ---- stage V^T tile [dim][key] (packed keypairs)
    {
      int p2 = t & 31, seg = t >> 5;  // keypair, dim-segment(8 dims)
      int j0 = jt * 64 + 2 * p2, j1 = j0 + 1;
      uint4 va = {0, 0, 0, 0}, vb = {0, 0, 0, 0};
      if (j0 < N_) va = *(const uint4*)(qkv + (size_t)(b * N_ + j0) * QKVC_ + 2 * D_ + h * 64 + seg * 8);
      if (j1 < N_) vb = *(const uint4*)(qkv + (size_t)(b * N_ + j1) * QKVC_ + 2 * D_ + h * 64 + seg * 8);
      const unsigned short* pa_ = (const unsigned short*)&va;
      const unsigned short* pb_ = (const unsigned short*)&vb;
      #pragma unroll
      for (int i = 0; i < 8; i++)
        vs[(seg * 8 + i) * 36 + p2] = (unsigned int)pa_[i] | ((unsigned int)pb_[i] << 16);
    }
    __syncthreads();
    // ---- QK: S^T[key][qrow] per wave: 4 key-tiles x 2 row-tiles
    f32x4 sacc[4][2];
    #pragma unroll
    for (int kt = 0; kt < 4; kt++) {
      s16x8 ka0 = *(const s16x8*)(&ks[(kt * 16 + m16) * 72 + quad * 8]);
      s16x8 ka1 = *(const s16x8*)(&ks[(kt * 16 + m16) * 72 + 32 + quad * 8]);
      #pragma unroll
      for (int nt = 0; nt < 2; nt++) {
        f32x4 s = (f32x4){0.f, 0.f, 0.f, 0.f};
        s = __builtin_amdgcn_mfma_f32_16x16x32_bf16(ka0, qb[nt][0], s, 0, 0, 0);
        s = __builtin_amdgcn_mfma_f32_16x16x32_bf16(ka1, qb[nt][1], s, 0, 0, 0);
        sacc[kt][nt] = s;
      }
    }
    // ---- P = exp(S*scale), masked; pack 4 consecutive keys -> b64 write
    #pragma unroll
    for (int kt = 0; kt < 4; kt++) {
      int kb = jt * 64 + kt * 16 + quad * 4;
      #pragma unroll
      for (int nt = 0; nt < 2; nt++) {
        f32x4 s = sacc[kt][nt];
        float p0 = (kb + 0 < N_) ? __expf(s[0] * SCALE_) : 0.f;
        float p1 = (kb + 1 < N_) ? __expf(s[1] * SCALE_) : 0.f;
        float p2 = (kb + 2 < N_) ? __expf(s[2] * SCALE_) : 0.f;
        float p3 = (kb + 3 < N_) ? __expf(s[3] * SCALE_) : 0.f;
        lp[nt] += p0 + p1 + p2 + p3;
        u16x4 pk = {f2bf(p0), f2bf(p1), f2bf(p2), f2bf(p3)};
        *(u16x4*)(&ps[(w * 32 + nt * 16 + m16) * 72 + kt * 16 + quad * 4]) = pk;
      }
    }
    __syncthreads();
    // ---- PV: O[qrow][dim] += P·V
    s16x8 pa[2][2];
    #pragma unroll
    for (int mt = 0; mt < 2; mt++)
      #pragma unroll
      for (int ks_ = 0; ks_ < 2; ks_++)
        pa[mt][ks_] = *(const s16x8*)(&ps[(w * 32 + mt * 16 + m16) * 72 + ks_ * 32 + quad * 8]);
    const short* vss = (const short*)vs;
    #pragma unroll
    for (int dt = 0; dt < 4; dt++) {
      s16x8 vb0 = *(const s16x8*)(&vss[(dt * 16 + m16) * 72 + quad * 8]);
      s16x8 vb1 = *(const s16x8*)(&vss[(dt * 16 + m16) * 72 + 32 + quad * 8]);
      #pragma unroll
      for (int mt = 0; mt < 2; mt++) {
        oacc[mt][dt] = __builtin_amdgcn_mfma_f32_16x16x32_bf16(pa[mt][0], vb0, oacc[mt][dt], 0, 0, 0);
        oacc[mt][dt] = __builtin_amdgcn_mfma_f32_16x16x32_bf16(pa[mt][1], vb1, oacc[mt][dt], 0, 0, 0);
      }
    }
  }
  // ---- l: reduce across the 4 quad-lanes holding each q-row
  #pragma unroll
  for (int nt = 0; nt < 2; nt++) {
    float l = lp[nt];
    l += __shfl_xor(l, 16, 64);
    l += __shfl_xor(l, 32, 64);
    if (quad == 0) lsum[w * 32 + nt * 16 + m16] = l;
  }
  __syncthreads();
  // ---- normalize + store (O layout: row=quad*4+reg+mt*16, dim=dt*16+m16)
  #pragma unroll
  for (int mt = 0; mt < 2; mt++) {
    float rinv[4];
    #pragma unroll
    for (int r = 0; r < 4; r++) rinv[r] = 1.0f / lsum[w * 32 + mt * 16 + quad * 4 + r];
    #pragma unroll
    for (int dt = 0; dt < 4; dt++) {
      #pragma unroll
      for (int r = 0; r < 4; r++) {
        int grow = b * N_ + qbase + w * 32 + mt * 16 + quad * 4 + r;
        attn_out[(size_t)grow * D_ + h * 64 + dt * 16 + m16] = f2bf(oacc[mt][dt][r] * rinv[r]);
      }
    }
  }
}

// ---------------- launch ----------------
extern "C" void kernel_launch(void* const* d_in, const int* in_sizes, int n_in,
                              void* d_out, int out_size, void* d_ws, size_t ws_size,
                              hipStream_t stream) {
  (void)in_sizes; (void)n_in; (void)out_size; (void)ws_size;
  const float* x     = (const float*)d_in[0];
  const float* canny = (const float*)d_in[1];
  const float* noise = (const float*)d_in[2];
  const float* lnw   = (const float*)d_in[3];
  const float* lnb   = (const float*)d_in[4];
  const float* wqkv  = (const float*)d_in[5];
  const float* wout  = (const float*)d_in[6];
  const float* bout  = (const float*)d_in[7];
  float* out = (float*)d_out;
  char* ws = (char*)d_ws;

  unsigned short* xn    = (unsigned short*)(ws);              // 8320*768 bf16 (reused as attn_out)
  unsigned short* wqkvT = (unsigned short*)(ws + 12779520);   // 2304*768
  unsigned short* woutT = (unsigned short*)(ws + 16318464);   // 768*768
  unsigned short* qkv   = (unsigned short*)(ws + 17498112);   // 8200*2304

  transpose_f2b<<<dim3(QKVC_ / 32, D_ / 32), 256, 0, stream>>>(wqkv, wqkvT, D_, QKVC_);
  transpose_f2b<<<dim3(D_ / 32, D_ / 32), 256, 0, stream>>>(wout, woutT, D_, D_);
  layernorm_k<<<dim3(ROWS_), 256, 0, stream>>>(x, lnw, lnb, xn);
  gemm_bt<false><<<dim3(QKVC_ / 128, ROWS_PAD_ / 128), 256, 0, stream>>>(
      xn, wqkvT, (void*)qkv, nullptr, ROWS_, QKVC_, D_);
  attn_cls<<<dim3(B_ * H_), 256, 0, stream>>>(qkv, canny, noise, xn);
  attn_main<<<dim3(8, H_, B_), 256, 0, stream>>>(qkv, xn);
  gemm_bt<true><<<dim3(D_ / 128, ROWS_PAD_ / 128), 256, 0, stream>>>(
      xn, woutT, (void*)out, bout, ROWS_, D_, D_);
}

// Round 5
// 266.788 us; speedup vs baseline: 3.5562x; 1.0251x over previous
//
#include <hip/hip_runtime.h>

#define B_ 8
#define N_ 1025
#define D_ 768
#define H_ 12
#define NP_ 1024
#define ROWS_ (B_*N_)        /* 8200 */
#define ROWS_PAD_ 8320       /* 65*128 */
#define QKVC_ 2304
#define SCALE_ 0.03608439182435161f  /* 768^-0.5 */
#define EPS_ 1e-5f

typedef float f32x4 __attribute__((ext_vector_type(4)));
typedef short s16x8 __attribute__((ext_vector_type(8)));
typedef unsigned short u16x4 __attribute__((ext_vector_type(4)));

// async global->LDS, 16B per lane; lds dest must be wave-uniform base + lane*16
#define GLD16(g, l) __builtin_amdgcn_global_load_lds( \
    (const __attribute__((address_space(1))) unsigned int*)(g), \
    (__attribute__((address_space(3))) unsigned int*)(l), 16, 0, 0)

__device__ __forceinline__ float blo(unsigned int u){
  union { unsigned int i; float f; } v; v.i = u << 16; return v.f;
}
__device__ __forceinline__ float bhi(unsigned int u){
  union { unsigned int i; float f; } v; v.i = u & 0xffff0000u; return v.f;
}
__device__ __forceinline__ float bf2f(unsigned short u){
  union { unsigned int i; float f; } v; v.i = ((unsigned int)u) << 16; return v.f;
}
__device__ __forceinline__ unsigned short f2bf(float f){
  union { unsigned int i; float f; } v; v.f = f;
  unsigned int b = v.i;
  b = b + 0x7fffu + ((b >> 16) & 1u);
  return (unsigned short)(b >> 16);
}

// ---------------- transpose (K x N) fp32 -> (N x K) bf16 ----------------
__global__ __launch_bounds__(256) void transpose_f2b(
    const float* __restrict__ src, unsigned short* __restrict__ dst,
    int K, int N) {
  __shared__ unsigned short tile[32][33];
  int kb = blockIdx.y * 32, nb = blockIdx.x * 32;
  int tx = threadIdx.x & 31, ty = threadIdx.x >> 5;  // 32 x 8
  #pragma unroll
  for (int i = 0; i < 4; i++) {
    int r = ty + i * 8;
    tile[r][tx] = f2bf(src[(size_t)(kb + r) * N + nb + tx]);
  }
  __syncthreads();
  #pragma unroll
  for (int i = 0; i < 4; i++) {
    int r = ty + i * 8;
    dst[(size_t)(nb + r) * K + kb + tx] = tile[tx][r];
  }
}

// ---------------- layernorm: x[8200][768] fp32 -> xn bf16 ----------------
__global__ __launch_bounds__(256) void layernorm_k(
    const float* __restrict__ x, const float* __restrict__ w,
    const float* __restrict__ b, unsigned short* __restrict__ xn) {
  int row = blockIdx.x;
  int t = threadIdx.x;
  const float* xr = x + (size_t)row * D_;
  float v0 = xr[t], v1 = xr[t + 256], v2 = xr[t + 512];
  __shared__ float rs[256], rq[256];
  rs[t] = v0 + v1 + v2;
  rq[t] = v0 * v0 + v1 * v1 + v2 * v2;
  __syncthreads();
  for (int st = 128; st > 0; st >>= 1) {
    if (t < st) { rs[t] += rs[t + st]; rq[t] += rq[t + st]; }
    __syncthreads();
  }
  float mean = rs[0] * (1.0f / 768.0f);
  float var = rq[0] * (1.0f / 768.0f) - mean * mean;
  var = var < 0.f ? 0.f : var;
  float rstd = rsqrtf(var + EPS_);
  unsigned short* yr = xn + (size_t)row * D_;
  yr[t]       = f2bf((v0 - mean) * rstd * w[t]       + b[t]);
  yr[t + 256] = f2bf((v1 - mean) * rstd * w[t + 256] + b[t + 256]);
  yr[t + 512] = f2bf((v2 - mean) * rstd * w[t + 512] + b[t + 512]);
}

// ---------------- GEMM: C[M][N] = A[M][K] * Bt[N][K]^T (+bias)
// bf16 in, fp32 acc; output bf16 (OF32=false) or fp32+bias (OF32=true).
// 128x128 tile, BK=32, global_load_lds 16B staging (m97 structure).
template <bool OF32>
__global__ __launch_bounds__(256) void gemm_bt(
    const unsigned short* __restrict__ A, const unsigned short* __restrict__ Bt,
    void* __restrict__ Cv, const float* __restrict__ bias,
    int Mvalid, int Nn, int Kk) {
  __shared__ short As[128 * 32];  // unpadded: global_load_lds needs lane-linear dest
  __shared__ short Bs[128 * 32];
  int t = threadIdx.x;
  int bm = blockIdx.y * 128, bn = blockIdx.x * 128;
  int lane = t & 63, wave = t >> 6;
  int wm = (wave & 1) * 64, wn = (wave >> 1) * 64;
  int m16 = lane & 15, quad = lane >> 4;
  f32x4 acc[4][4];
  #pragma unroll
  for (int i = 0; i < 4; i++)
    #pragma unroll
    for (int j = 0; j < 4; j++) acc[i][j] = (f32x4){0.f, 0.f, 0.f, 0.f};

  // staging: thread t owns 16B chunks t and t+256 of each 8KB tile
  int e0 = t * 8;             // element offset of chunk t (8 shorts = 16B)
  int e1 = (t + 256) * 8;
  int r0 = e0 >> 5, c0 = e0 & 31;
  int r1 = e1 >> 5, c1 = e1 & 31;
  const unsigned short* a0p = A + (size_t)(bm + r0) * Kk + c0;
  const unsigned short* a1p = A + (size_t)(bm + r1) * Kk + c1;
  const unsigned short* b0p = Bt + (size_t)(bn + r0) * Kk + c0;
  const unsigned short* b1p = Bt + (size_t)(bn + r1) * Kk + c1;

  int ksteps = Kk >> 5;
  for (int kt = 0; kt < ksteps; kt++) {
    __syncthreads();
    GLD16(a0p + kt * 32, &As[e0]);
    GLD16(a1p + kt * 32, &As[e1]);
    GLD16(b0p + kt * 32, &Bs[e0]);
    GLD16(b1p + kt * 32, &Bs[e1]);
    __syncthreads();
    s16x8 af[4], bfr[4];
    #pragma unroll
    for (int i = 0; i < 4; i++) {
      af[i]  = *(const s16x8*)(&As[(wm + i * 16 + m16) * 32 + quad * 8]);
      bfr[i] = *(const s16x8*)(&Bs[(wn + i * 16 + m16) * 32 + quad * 8]);
    }
    #pragma unroll
    for (int i = 0; i < 4; i++)
      #pragma unroll
      for (int j = 0; j < 4; j++)
        acc[i][j] = __builtin_amdgcn_mfma_f32_16x16x32_bf16(af[i], bfr[j], acc[i][j], 0, 0, 0);
  }
  #pragma unroll
  for (int j = 0; j < 4; j++) {
    int col = bn + wn + j * 16 + m16;
    float bv = bias ? bias[col] : 0.f;
    #pragma unroll
    for (int i = 0; i < 4; i++) {
      #pragma unroll
      for (int r = 0; r < 4; r++) {
        int row = bm + wm + i * 16 + quad * 4 + r;
        if (row < Mvalid) {
          if (OF32) ((float*)Cv)[(size_t)row * Nn + col] = acc[i][j][r] + bv;
          else ((unsigned short*)Cv)[(size_t)row * Nn + col] = f2bf(acc[i][j][r] + bv);
        }
      }
    }
  }
}

// ---------------- block-wide sum helper ----------------
__device__ __forceinline__ float block_sum(float v, float* red) {
  int t = threadIdx.x;
  red[t] = v;
  __syncthreads();
  for (int st = 128; st > 0; st >>= 1) {
    if (t < st) red[t] += red[t + st];
    __syncthreads();
  }
  float r = red[0];
  __syncthreads();
  return r;
}

// ---------------- CLS-row attention (row 0 of each (b,h)) ----------------
__global__ __launch_bounds__(256) void attn_cls(
    const unsigned short* __restrict__ qkv, const float* __restrict__ canny,
    const float* __restrict__ noise, unsigned short* __restrict__ attn_out) {
  int bh = blockIdx.x;
  int b = bh / H_, h = bh % H_;
  int t = threadIdx.x;
  __shared__ float s[N_];
  __shared__ float red[256];
  __shared__ float q[64];
  __shared__ float pvred[64 * 33];  // [dim][group], +1 pad -> conflict-free

  if (t < 64) q[t] = bf2f(qkv[(size_t)(b * N_) * QKVC_ + h * 64 + t]);
  __syncthreads();

  // QK: vectorized uint4 loads (8 x 16B per key row)
  for (int j = t; j < N_; j += 256) {
    const unsigned short* krow = qkv + (size_t)(b * N_ + j) * QKVC_ + D_ + h * 64;
    float dot = 0.f;
    #pragma unroll
    for (int c = 0; c < 8; c++) {
      uint4 kk = *(const uint4*)(krow + c * 8);
      dot += q[c*8+0]*blo(kk.x) + q[c*8+1]*bhi(kk.x)
           + q[c*8+2]*blo(kk.y) + q[c*8+3]*bhi(kk.y)
           + q[c*8+4]*blo(kk.z) + q[c*8+5]*bhi(kk.z)
           + q[c*8+6]*blo(kk.w) + q[c*8+7]*bhi(kk.w);
    }
    s[j] = dot * SCALE_;
  }
  float cp = 0.f, npp = 0.f;
  for (int j = t; j < NP_; j += 256) {
    cp  += canny[b * NP_ + j] + 1.0f;
    npp += noise[b * NP_ + j];
  }
  float csum = block_sum(cp, red);
  float nsum = block_sum(npp, red);
  float e1 = 0.f;
  for (int j = t; j < N_; j += 256) if (j >= 1) e1 += __expf(s[j]);
  float sum1 = block_sum(e1, red);
  for (int j = t; j < N_; j += 256) {
    if (j >= 1) {
      s[j] = __expf(s[j]) / sum1
           + (canny[b * NP_ + j - 1] + 1.0f) / csum
           + noise[b * NP_ + j - 1] / nsum;
    }
  }
  __syncthreads();
  float e2 = 0.f;
  for (int j = t; j < N_; j += 256) { float e = __expf(s[j]); s[j] = e; e2 += e; }
  float sum2 = block_sum(e2, red);
  // PV: thread owns dim-octet o (8 dims), strides 32 rows -> 1 uint4 load/iter
  {
    int o = t & 7, g = t >> 3;
    float a[8] = {0.f, 0.f, 0.f, 0.f, 0.f, 0.f, 0.f, 0.f};
    for (int j = g; j < N_; j += 32) {
      float sv = s[j];
      uint4 vv = *(const uint4*)(qkv + (size_t)(b * N_ + j) * QKVC_ + 2 * D_ + h * 64 + o * 8);
      a[0] += sv * blo(vv.x); a[1] += sv * bhi(vv.x);
      a[2] += sv * blo(vv.y); a[3] += sv * bhi(vv.y);
      a[4] += sv * blo(vv.z); a[5] += sv * bhi(vv.z);
      a[6] += sv * blo(vv.w); a[7] += sv * bhi(vv.w);
    }
    #pragma unroll
    for (int i = 0; i < 8; i++) pvred[(o * 8 + i) * 33 + g] = a[i];
  }
  __syncthreads();
  if (t < 64) {
    float acc = 0.f;
    #pragma unroll
    for (int u = 0; u < 32; u++) acc += pvred[t * 33 + u];
    attn_out[(size_t)(b * N_) * D_ + h * 64 + t] = f2bf(acc / sum2);
  }
}

// ---------------- main attention (MFMA): rows 1..1024, 128 rows/block ----------------
// S^T = K·Q^T via mfma (A=K[key][hd], B=Q[row][hd]) so each lane holds P for a
// fixed q-row (col=lane&15) and 4 consecutive keys (row=quad*4+reg) -> b64 P
// writes to LDS in PV A-operand layout. V^T staged per tile for the PV B-operand.
__global__ __launch_bounds__(256) void attn_main(
    const unsigned short* __restrict__ qkv, unsigned short* __restrict__ attn_out) {
  int tile = blockIdx.x;  // 0..7 (128 q-rows each)
  int h = blockIdx.y;     // 0..11
  int b = blockIdx.z;     // 0..7
  int t = threadIdx.x;
  int lane = t & 63, w = t >> 6;
  int m16 = lane & 15, quad = lane >> 4;

  __shared__ short ps[128 * 72];        // Q staging, then P tiles [row][key]
  __shared__ short ks[64 * 72];         // K tile [key][hd]
  __shared__ unsigned int vs[64 * 36];  // V^T tile [dim][keypair]
  __shared__ float lsum[128];

  int qbase = 1 + tile * 128;

  // ---- stage Q (each wave stages exactly its own 32 rows: t>>1 in [32w,32w+31])
  {
    int r = t >> 1, seg = (t & 1) * 32;
    const uint4* src = (const uint4*)(qkv + (size_t)(b * N_ + qbase + r) * QKVC_ + h * 64 + seg);
    uint4 u0 = src[0], u1 = src[1], u2 = src[2], u3 = src[3];
    *(uint4*)(&ps[r * 72 + seg])      = u0;
    *(uint4*)(&ps[r * 72 + seg + 8])  = u1;
    *(uint4*)(&ps[r * 72 + seg + 16]) = u2;
    *(uint4*)(&ps[r * 72 + seg + 24]) = u3;
  }
  // ---- Q B-operand fragments (lane n=m16 -> q-row, k=hd quad*8+j), held in regs
  s16x8 qb[2][2];
  #pragma unroll
  for (int nt = 0; nt < 2; nt++)
    #pragma unroll
    for (int ks_ = 0; ks_ < 2; ks_++)
      qb[nt][ks_] = *(const s16x8*)(&ps[(w * 32 + nt * 16 + m16) * 72 + ks_ * 32 + quad * 8]);

  f32x4 oacc[2][4];
  #pragma unroll
  for (int mt = 0; mt < 2; mt++)
    #pragma unroll
    for (int dt = 0; dt < 4; dt++) oacc[mt][dt] = (f32x4){0.f, 0.f, 0.f, 0.f};
  float lp[2] = {0.f, 0.f};

  for (int jt = 0; jt < 17; jt++) {
    __syncthreads();  // prior QK(ks) + PV(vs) reads complete
    // ---- stage K tile [key][hd]
    {
      int key = t >> 2, seg = (t & 3) * 16;
      int j = jt * 64 + key;
      uint4 k0 = {0, 0, 0, 0}, k1 = {0, 0, 0, 0};
      if (j < N_) {
        const uint4* src = (const uint4*)(qkv + (size_t)(b * N_ + j) * QKVC_ + D_ + h * 64 + seg);
        k0 = src[0]; k1 = src[1];
      }
      *(uint4*)(&ks[key * 72 + seg])     = k0;
      *(uint4*)(&ks[key * 72 + seg + 8]) = k1;
    }
    // ---- stage V^T tile [dim][key] (packed keypairs)
    {
      int p2 = t & 31, seg = t >> 5;  // keypair, dim-segment(8 dims)
      int j0 = jt * 64 + 2 * p2, j1 = j0 + 1;
      uint4 va = {0, 0, 0, 0}, vb = {0, 0, 0, 0};
      if (j0 < N_) va = *(const uint4*)(qkv + (size_t)(b * N_ + j0) * QKVC_ + 2 * D_ + h * 64 + seg * 8);
      if (j1 < N_) vb = *(const uint4*)(qkv + (size_t)(b * N_ + j1) * QKVC_ + 2 * D_ + h * 64 + seg * 8);
      const unsigned short* pa_ = (const unsigned short*)&va;
      const unsigned short* pb_ = (const unsigned short*)&vb;
      #pragma unroll
      for (int i = 0; i < 8; i++)
        vs[(seg * 8 + i) * 36 + p2] = (unsigned int)pa_[i] | ((unsigned int)pb_[i] << 16);
    }
    __syncthreads();
    // ---- QK: S^T[key][qrow] per wave: 4 key-tiles x 2 row-tiles
    f32x4 sacc[4][2];
    #pragma unroll
    for (int kt = 0; kt < 4; kt++) {
      s16x8 ka0 = *(const s16x8*)(&ks[(kt * 16 + m16) * 72 + quad * 8]);
      s16x8 ka1 = *(const s16x8*)(&ks[(kt * 16 + m16) * 72 + 32 + quad * 8]);
      #pragma unroll
      for (int nt = 0; nt < 2; nt++) {
        f32x4 s = (f32x4){0.f, 0.f, 0.f, 0.f};
        s = __builtin_amdgcn_mfma_f32_16x16x32_bf16(ka0, qb[nt][0], s, 0, 0, 0);
        s = __builtin_amdgcn_mfma_f32_16x16x32_bf16(ka1, qb[nt][1], s, 0, 0, 0);
        sacc[kt][nt] = s;
      }
    }
    // ---- P = exp(S*scale), masked; pack 4 consecutive keys -> b64 write
    #pragma unroll
    for (int kt = 0; kt < 4; kt++) {
      int kb = jt * 64 + kt * 16 + quad * 4;
      #pragma unroll
      for (int nt = 0; nt < 2; nt++) {
        f32x4 s = sacc[kt][nt];
        float p0 = (kb + 0 < N_) ? __expf(s[0] * SCALE_) : 0.f;
        float p1 = (kb + 1 < N_) ? __expf(s[1] * SCALE_) : 0.f;
        float p2 = (kb + 2 < N_) ? __expf(s[2] * SCALE_) : 0.f;
        float p3 = (kb + 3 < N_) ? __expf(s[3] * SCALE_) : 0.f;
        lp[nt] += p0 + p1 + p2 + p3;
        u16x4 pk = {f2bf(p0), f2bf(p1), f2bf(p2), f2bf(p3)};
        *(u16x4*)(&ps[(w * 32 + nt * 16 + m16) * 72 + kt * 16 + quad * 4]) = pk;
      }
    }
    __syncthreads();
    // ---- PV: O[qrow][dim] += P·V
    s16x8 pa[2][2];
    #pragma unroll
    for (int mt = 0; mt < 2; mt++)
      #pragma unroll
      for (int ks_ = 0; ks_ < 2; ks_++)
        pa[mt][ks_] = *(const s16x8*)(&ps[(w * 32 + mt * 16 + m16) * 72 + ks_ * 32 + quad * 8]);
    const short* vss = (const short*)vs;
    #pragma unroll
    for (int dt = 0; dt < 4; dt++) {
      s16x8 vb0 = *(const s16x8*)(&vss[(dt * 16 + m16) * 72 + quad * 8]);
      s16x8 vb1 = *(const s16x8*)(&vss[(dt * 16 + m16) * 72 + 32 + quad * 8]);
      #pragma unroll
      for (int mt = 0; mt < 2; mt++) {
        oacc[mt][dt] = __builtin_amdgcn_mfma_f32_16x16x32_bf16(pa[mt][0], vb0, oacc[mt][dt], 0, 0, 0);
        oacc[mt][dt] = __builtin_amdgcn_mfma_f32_16x16x32_bf16(pa[mt][1], vb1, oacc[mt][dt], 0, 0, 0);
      }
    }
  }
  // ---- l: reduce across the 4 quad-lanes holding each q-row
  #pragma unroll
  for (int nt = 0; nt < 2; nt++) {
    float l = lp[nt];
    l += __shfl_xor(l, 16, 64);
    l += __shfl_xor(l, 32, 64);
    if (quad == 0) lsum[w * 32 + nt * 16 + m16] = l;
  }
  __syncthreads();
  // ---- normalize + store (O layout: row=quad*4+reg+mt*16, dim=dt*16+m16)
  #pragma unroll
  for (int mt = 0; mt < 2; mt++) {
    float rinv[4];
    #pragma unroll
    for (int r = 0; r < 4; r++) rinv[r] = 1.0f / lsum[w * 32 + mt * 16 + quad * 4 + r];
    #pragma unroll
    for (int dt = 0; dt < 4; dt++) {
      #pragma unroll
      for (int r = 0; r < 4; r++) {
        int grow = b * N_ + qbase + w * 32 + mt * 16 + quad * 4 + r;
        attn_out[(size_t)grow * D_ + h * 64 + dt * 16 + m16] = f2bf(oacc[mt][dt][r] * rinv[r]);
      }
    }
  }
}

// ---------------- launch ----------------
extern "C" void kernel_launch(void* const* d_in, const int* in_sizes, int n_in,
                              void* d_out, int out_size, void* d_ws, size_t ws_size,
                              hipStream_t stream) {
  (void)in_sizes; (void)n_in; (void)out_size; (void)ws_size;
  const float* x     = (const float*)d_in[0];
  const float* canny = (const float*)d_in[1];
  const float* noise = (const float*)d_in[2];
  const float* lnw   = (const float*)d_in[3];
  const float* lnb   = (const float*)d_in[4];
  const float* wqkv  = (const float*)d_in[5];
  const float* wout  = (const float*)d_in[6];
  const float* bout  = (const float*)d_in[7];
  float* out = (float*)d_out;
  char* ws = (char*)d_ws;

  unsigned short* xn    = (unsigned short*)(ws);              // 8320*768 bf16 (reused as attn_out)
  unsigned short* wqkvT = (unsigned short*)(ws + 12779520);   // 2304*768
  unsigned short* woutT = (unsigned short*)(ws + 16318464);   // 768*768
  unsigned short* qkv   = (unsigned short*)(ws + 17498112);   // 8200*2304

  transpose_f2b<<<dim3(QKVC_ / 32, D_ / 32), 256, 0, stream>>>(wqkv, wqkvT, D_, QKVC_);
  transpose_f2b<<<dim3(D_ / 32, D_ / 32), 256, 0, stream>>>(wout, woutT, D_, D_);
  layernorm_k<<<dim3(ROWS_), 256, 0, stream>>>(x, lnw, lnb, xn);
  gemm_bt<false><<<dim3(QKVC_ / 128, ROWS_PAD_ / 128), 256, 0, stream>>>(
      xn, wqkvT, (void*)qkv, nullptr, ROWS_, QKVC_, D_);
  attn_cls<<<dim3(B_ * H_), 256, 0, stream>>>(qkv, canny, noise, xn);
  attn_main<<<dim3(8, H_, B_), 256, 0, stream>>>(qkv, xn);
  gemm_bt<true><<<dim3(D_ / 128, ROWS_PAD_ / 128), 256, 0, stream>>>(
      xn, woutT, (void*)out, bout, ROWS_, D_, D_);
}

// Round 6
// 257.454 us; speedup vs baseline: 3.6852x; 1.0363x over previous
//
#include <hip/hip_runtime.h>

#define B_ 8
#define N_ 1025
#define D_ 768
#define H_ 12
#define NP_ 1024
#define ROWS_ (B_*N_)        /* 8200 */
#define ROWS_PAD_ 8320       /* 65*128 */
#define QKVC_ 2304
#define SCALE_ 0.03608439182435161f  /* 768^-0.5 */
#define EPS_ 1e-5f

typedef float f32x4 __attribute__((ext_vector_type(4)));
typedef short s16x8 __attribute__((ext_vector_type(8)));
typedef unsigned short u16x4 __attribute__((ext_vector_type(4)));

// async global->LDS, 16B per lane; lds dest must be wave-uniform base + lane*16
#define GLD16(g, l) __builtin_amdgcn_global_load_lds( \
    (const __attribute__((address_space(1))) unsigned int*)(g), \
    (__attribute__((address_space(3))) unsigned int*)(l), 16, 0, 0)

__device__ __forceinline__ float blo(unsigned int u){
  union { unsigned int i; float f; } v; v.i = u << 16; return v.f;
}
__device__ __forceinline__ float bhi(unsigned int u){
  union { unsigned int i; float f; } v; v.i = u & 0xffff0000u; return v.f;
}
__device__ __forceinline__ float bf2f(unsigned short u){
  union { unsigned int i; float f; } v; v.i = ((unsigned int)u) << 16; return v.f;
}
__device__ __forceinline__ unsigned short f2bf(float f){
  union { unsigned int i; float f; } v; v.f = f;
  unsigned int b = v.i;
  b = b + 0x7fffu + ((b >> 16) & 1u);
  return (unsigned short)(b >> 16);
}

// ---------------- transpose (K x N) fp32 -> (N x K) bf16 ----------------
__global__ __launch_bounds__(256) void transpose_f2b(
    const float* __restrict__ src, unsigned short* __restrict__ dst,
    int K, int N) {
  __shared__ unsigned short tile[32][33];
  int kb = blockIdx.y * 32, nb = blockIdx.x * 32;
  int tx = threadIdx.x & 31, ty = threadIdx.x >> 5;  // 32 x 8
  #pragma unroll
  for (int i = 0; i < 4; i++) {
    int r = ty + i * 8;
    tile[r][tx] = f2bf(src[(size_t)(kb + r) * N + nb + tx]);
  }
  __syncthreads();
  #pragma unroll
  for (int i = 0; i < 4; i++) {
    int r = ty + i * 8;
    dst[(size_t)(nb + r) * K + kb + tx] = tile[tx][r];
  }
}

// ---------------- layernorm: x[8200][768] fp32 -> xn bf16 ----------------
__global__ __launch_bounds__(256) void layernorm_k(
    const float* __restrict__ x, const float* __restrict__ w,
    const float* __restrict__ b, unsigned short* __restrict__ xn) {
  int row = blockIdx.x;
  int t = threadIdx.x;
  const float* xr = x + (size_t)row * D_;
  float v0 = xr[t], v1 = xr[t + 256], v2 = xr[t + 512];
  __shared__ float rs[256], rq[256];
  rs[t] = v0 + v1 + v2;
  rq[t] = v0 * v0 + v1 * v1 + v2 * v2;
  __syncthreads();
  for (int st = 128; st > 0; st >>= 1) {
    if (t < st) { rs[t] += rs[t + st]; rq[t] += rq[t + st]; }
    __syncthreads();
  }
  float mean = rs[0] * (1.0f / 768.0f);
  float var = rq[0] * (1.0f / 768.0f) - mean * mean;
  var = var < 0.f ? 0.f : var;
  float rstd = rsqrtf(var + EPS_);
  unsigned short* yr = xn + (size_t)row * D_;
  yr[t]       = f2bf((v0 - mean) * rstd * w[t]       + b[t]);
  yr[t + 256] = f2bf((v1 - mean) * rstd * w[t + 256] + b[t + 256]);
  yr[t + 512] = f2bf((v2 - mean) * rstd * w[t + 512] + b[t + 512]);
}

// ---------------- GEMM: C[M][N] = A[M][K] * Bt[N][K]^T (+bias)
// bf16 in, fp32 acc; output bf16 (OF32=false) or fp32+bias (OF32=true).
// 128x128 tile, BK=64 as two 128x32 K-half tiles (keeps lane-linear
// global_load_lds layout + m97-validated 64B-stride ds_read pattern).
// 32 MFMA per barrier per wave, 12 K-iterations at K=768.
template <bool OF32>
__global__ __launch_bounds__(256) void gemm_bt(
    const unsigned short* __restrict__ A, const unsigned short* __restrict__ Bt,
    void* __restrict__ Cv, const float* __restrict__ bias,
    int Mvalid, int Nn, int Kk) {
  __shared__ short As[2][128 * 32];
  __shared__ short Bs[2][128 * 32];
  int t = threadIdx.x;
  int bm = blockIdx.y * 128, bn = blockIdx.x * 128;
  int lane = t & 63, wave = t >> 6;
  int wm = (wave & 1) * 64, wn = (wave >> 1) * 64;
  int m16 = lane & 15, quad = lane >> 4;
  f32x4 acc[4][4];
  #pragma unroll
  for (int i = 0; i < 4; i++)
    #pragma unroll
    for (int j = 0; j < 4; j++) acc[i][j] = (f32x4){0.f, 0.f, 0.f, 0.f};

  // staging: thread t owns 16B chunks t and t+256 of each 8KB half-tile
  int e0 = t * 8;             // element offset of chunk t (8 shorts = 16B)
  int e1 = (t + 256) * 8;
  int r0 = e0 >> 5, c0 = e0 & 31;
  int r1 = e1 >> 5, c1 = e1 & 31;
  const unsigned short* a0p = A + (size_t)(bm + r0) * Kk + c0;
  const unsigned short* a1p = A + (size_t)(bm + r1) * Kk + c1;
  const unsigned short* b0p = Bt + (size_t)(bn + r0) * Kk + c0;
  const unsigned short* b1p = Bt + (size_t)(bn + r1) * Kk + c1;

  int ksteps = Kk >> 6;  // BK=64
  for (int kt = 0; kt < ksteps; kt++) {
    int k0 = kt * 64, k1 = kt * 64 + 32;
    __syncthreads();
    GLD16(a0p + k0, &As[0][e0]);
    GLD16(a1p + k0, &As[0][e1]);
    GLD16(a0p + k1, &As[1][e0]);
    GLD16(a1p + k1, &As[1][e1]);
    GLD16(b0p + k0, &Bs[0][e0]);
    GLD16(b1p + k0, &Bs[0][e1]);
    GLD16(b0p + k1, &Bs[1][e0]);
    GLD16(b1p + k1, &Bs[1][e1]);
    __syncthreads();
    #pragma unroll
    for (int hh = 0; hh < 2; hh++) {
      s16x8 af[4], bfr[4];
      #pragma unroll
      for (int i = 0; i < 4; i++) {
        af[i]  = *(const s16x8*)(&As[hh][(wm + i * 16 + m16) * 32 + quad * 8]);
        bfr[i] = *(const s16x8*)(&Bs[hh][(wn + i * 16 + m16) * 32 + quad * 8]);
      }
      #pragma unroll
      for (int i = 0; i < 4; i++)
        #pragma unroll
        for (int j = 0; j < 4; j++)
          acc[i][j] = __builtin_amdgcn_mfma_f32_16x16x32_bf16(af[i], bfr[j], acc[i][j], 0, 0, 0);
    }
  }
  #pragma unroll
  for (int j = 0; j < 4; j++) {
    int col = bn + wn + j * 16 + m16;
    float bv = bias ? bias[col] : 0.f;
    #pragma unroll
    for (int i = 0; i < 4; i++) {
      #pragma unroll
      for (int r = 0; r < 4; r++) {
        int row = bm + wm + i * 16 + quad * 4 + r;
        if (row < Mvalid) {
          if (OF32) ((float*)Cv)[(size_t)row * Nn + col] = acc[i][j][r] + bv;
          else ((unsigned short*)Cv)[(size_t)row * Nn + col] = f2bf(acc[i][j][r] + bv);
        }
      }
    }
  }
}

// ---------------- block-wide sum helper ----------------
__device__ __forceinline__ float block_sum(float v, float* red) {
  int t = threadIdx.x;
  red[t] = v;
  __syncthreads();
  for (int st = 128; st > 0; st >>= 1) {
    if (t < st) red[t] += red[t + st];
    __syncthreads();
  }
  float r = red[0];
  __syncthreads();
  return r;
}

// ---------------- CLS-row attention (row 0 of each (b,h)) ----------------
__global__ __launch_bounds__(256) void attn_cls(
    const unsigned short* __restrict__ qkv, const float* __restrict__ canny,
    const float* __restrict__ noise, unsigned short* __restrict__ attn_out) {
  int bh = blockIdx.x;
  int b = bh / H_, h = bh % H_;
  int t = threadIdx.x;
  __shared__ float s[N_];
  __shared__ float red[256];
  __shared__ float q[64];
  __shared__ float pvred[64 * 33];  // [dim][group], +1 pad -> conflict-free

  if (t < 64) q[t] = bf2f(qkv[(size_t)(b * N_) * QKVC_ + h * 64 + t]);
  __syncthreads();

  // QK: vectorized uint4 loads (8 x 16B per key row)
  for (int j = t; j < N_; j += 256) {
    const unsigned short* krow = qkv + (size_t)(b * N_ + j) * QKVC_ + D_ + h * 64;
    float dot = 0.f;
    #pragma unroll
    for (int c = 0; c < 8; c++) {
      uint4 kk = *(const uint4*)(krow + c * 8);
      dot += q[c*8+0]*blo(kk.x) + q[c*8+1]*bhi(kk.x)
           + q[c*8+2]*blo(kk.y) + q[c*8+3]*bhi(kk.y)
           + q[c*8+4]*blo(kk.z) + q[c*8+5]*bhi(kk.z)
           + q[c*8+6]*blo(kk.w) + q[c*8+7]*bhi(kk.w);
    }
    s[j] = dot * SCALE_;
  }
  float cp = 0.f, npp = 0.f;
  for (int j = t; j < NP_; j += 256) {
    cp  += canny[b * NP_ + j] + 1.0f;
    npp += noise[b * NP_ + j];
  }
  float csum = block_sum(cp, red);
  float nsum = block_sum(npp, red);
  float e1 = 0.f;
  for (int j = t; j < N_; j += 256) if (j >= 1) e1 += __expf(s[j]);
  float sum1 = block_sum(e1, red);
  for (int j = t; j < N_; j += 256) {
    if (j >= 1) {
      s[j] = __expf(s[j]) / sum1
           + (canny[b * NP_ + j - 1] + 1.0f) / csum
           + noise[b * NP_ + j - 1] / nsum;
    }
  }
  __syncthreads();
  float e2 = 0.f;
  for (int j = t; j < N_; j += 256) { float e = __expf(s[j]); s[j] = e; e2 += e; }
  float sum2 = block_sum(e2, red);
  // PV: thread owns dim-octet o (8 dims), strides 32 rows -> 1 uint4 load/iter
  {
    int o = t & 7, g = t >> 3;
    float a[8] = {0.f, 0.f, 0.f, 0.f, 0.f, 0.f, 0.f, 0.f};
    for (int j = g; j < N_; j += 32) {
      float sv = s[j];
      uint4 vv = *(const uint4*)(qkv + (size_t)(b * N_ + j) * QKVC_ + 2 * D_ + h * 64 + o * 8);
      a[0] += sv * blo(vv.x); a[1] += sv * bhi(vv.x);
      a[2] += sv * blo(vv.y); a[3] += sv * bhi(vv.y);
      a[4] += sv * blo(vv.z); a[5] += sv * bhi(vv.z);
      a[6] += sv * blo(vv.w); a[7] += sv * bhi(vv.w);
    }
    #pragma unroll
    for (int i = 0; i < 8; i++) pvred[(o * 8 + i) * 33 + g] = a[i];
  }
  __syncthreads();
  if (t < 64) {
    float acc = 0.f;
    #pragma unroll
    for (int u = 0; u < 32; u++) acc += pvred[t * 33 + u];
    attn_out[(size_t)(b * N_) * D_ + h * 64 + t] = f2bf(acc / sum2);
  }
}

// ---------------- main attention (MFMA): rows 1..1024, 128 rows/block ----------------
// S^T = K·Q^T via mfma (A=K[key][hd], B=Q[row][hd]) so each lane holds P for a
// fixed q-row (col=lane&15) and 4 consecutive keys (row=quad*4+reg) -> b64 P
// writes to LDS in PV A-operand layout. V^T staged per tile for the PV B-operand.
__global__ __launch_bounds__(256) void attn_main(
    const unsigned short* __restrict__ qkv, unsigned short* __restrict__ attn_out) {
  int tile = blockIdx.x;  // 0..7 (128 q-rows each)
  int h = blockIdx.y;     // 0..11
  int b = blockIdx.z;     // 0..7
  int t = threadIdx.x;
  int lane = t & 63, w = t >> 6;
  int m16 = lane & 15, quad = lane >> 4;

  __shared__ short ps[128 * 72];        // Q staging, then P tiles [row][key]
  __shared__ short ks[64 * 72];         // K tile [key][hd]
  __shared__ unsigned int vs[64 * 36];  // V^T tile [dim][keypair]
  __shared__ float lsum[128];

  int qbase = 1 + tile * 128;

  // ---- stage Q (each wave stages exactly its own 32 rows: t>>1 in [32w,32w+31])
  {
    int r = t >> 1, seg = (t & 1) * 32;
    const uint4* src = (const uint4*)(qkv + (size_t)(b * N_ + qbase + r) * QKVC_ + h * 64 + seg);
    uint4 u0 = src[0], u1 = src[1], u2 = src[2], u3 = src[3];
    *(uint4*)(&ps[r * 72 + seg])      = u0;
    *(uint4*)(&ps[r * 72 + seg + 8])  = u1;
    *(uint4*)(&ps[r * 72 + seg + 16]) = u2;
    *(uint4*)(&ps[r * 72 + seg + 24]) = u3;
  }
  // ---- Q B-operand fragments (lane n=m16 -> q-row, k=hd quad*8+j), held in regs
  s16x8 qb[2][2];
  #pragma unroll
  for (int nt = 0; nt < 2; nt++)
    #pragma unroll
    for (int ks_ = 0; ks_ < 2; ks_++)
      qb[nt][ks_] = *(const s16x8*)(&ps[(w * 32 + nt * 16 + m16) * 72 + ks_ * 32 + quad * 8]);

  f32x4 oacc[2][4];
  #pragma unroll
  for (int mt = 0; mt < 2; mt++)
    #pragma unroll
    for (int dt = 0; dt < 4; dt++) oacc[mt][dt] = (f32x4){0.f, 0.f, 0.f, 0.f};
  float lp[2] = {0.f, 0.f};

  for (int jt = 0; jt < 17; jt++) {
    __syncthreads();  // prior QK(ks) + PV(vs) reads complete
    // ---- stage K tile [key][hd]
    {
      int key = t >> 2, seg = (t & 3) * 16;
      int j = jt * 64 + key;
      uint4 k0 = {0, 0, 0, 0}, k1 = {0, 0, 0, 0};
      if (j < N_) {
        const uint4* src = (const uint4*)(qkv + (size_t)(b * N_ + j) * QKVC_ + D_ + h * 64 + seg);
        k0 = src[0]; k1 = src[1];
      }
      *(uint4*)(&ks[key * 72 + seg])     = k0;
      *(uint4*)(&ks[key * 72 + seg + 8]) = k1;
    }
    // ---- stage V^T tile [dim][key] (packed keypairs)
    {
      int p2 = t & 31, seg = t >> 5;  // keypair, dim-segment(8 dims)
      int j0 = jt * 64 + 2 * p2, j1 = j0 + 1;
      uint4 va = {0, 0, 0, 0}, vb = {0, 0, 0, 0};
      if (j0 < N_) va = *(const uint4*)(qkv + (size_t)(b * N_ + j0) * QKVC_ + 2 * D_ + h * 64 + seg * 8);
      if (j1 < N_) vb = *(const uint4*)(qkv + (size_t)(b * N_ + j1) * QKVC_ + 2 * D_ + h * 64 + seg * 8);
      const unsigned short* pa_ = (const unsigned short*)&va;
      const unsigned short* pb_ = (const unsigned short*)&vb;
      #pragma unroll
      for (int i = 0; i < 8; i++)
        vs[(seg * 8 + i) * 36 + p2] = (unsigned int)pa_[i] | ((unsigned int)pb_[i] << 16);
    }
    __syncthreads();
    // ---- QK: S^T[key][qrow] per wave: 4 key-tiles x 2 row-tiles
    f32x4 sacc[4][2];
    #pragma unroll
    for (int kt = 0; kt < 4; kt++) {
      s16x8 ka0 = *(const s16x8*)(&ks[(kt * 16 + m16) * 72 + quad * 8]);
      s16x8 ka1 = *(const s16x8*)(&ks[(kt * 16 + m16) * 72 + 32 + quad * 8]);
      #pragma unroll
      for (int nt = 0; nt < 2; nt++) {
        f32x4 s = (f32x4){0.f, 0.f, 0.f, 0.f};
        s = __builtin_amdgcn_mfma_f32_16x16x32_bf16(ka0, qb[nt][0], s, 0, 0, 0);
        s = __builtin_amdgcn_mfma_f32_16x16x32_bf16(ka1, qb[nt][1], s, 0, 0, 0);
        sacc[kt][nt] = s;
      }
    }
    // ---- P = exp(S*scale), masked; pack 4 consecutive keys -> b64 write
    #pragma unroll
    for (int kt = 0; kt < 4; kt++) {
      int kb = jt * 64 + kt * 16 + quad * 4;
      #pragma unroll
      for (int nt = 0; nt < 2; nt++) {
        f32x4 s = sacc[kt][nt];
        float p0 = (kb + 0 < N_) ? __expf(s[0] * SCALE_) : 0.f;
        float p1 = (kb + 1 < N_) ? __expf(s[1] * SCALE_) : 0.f;
        float p2 = (kb + 2 < N_) ? __expf(s[2] * SCALE_) : 0.f;
        float p3 = (kb + 3 < N_) ? __expf(s[3] * SCALE_) : 0.f;
        lp[nt] += p0 + p1 + p2 + p3;
        u16x4 pk = {f2bf(p0), f2bf(p1), f2bf(p2), f2bf(p3)};
        *(u16x4*)(&ps[(w * 32 + nt * 16 + m16) * 72 + kt * 16 + quad * 4]) = pk;
      }
    }
    __syncthreads();
    // ---- PV: O[qrow][dim] += P·V
    s16x8 pa[2][2];
    #pragma unroll
    for (int mt = 0; mt < 2; mt++)
      #pragma unroll
      for (int ks_ = 0; ks_ < 2; ks_++)
        pa[mt][ks_] = *(const s16x8*)(&ps[(w * 32 + mt * 16 + m16) * 72 + ks_ * 32 + quad * 8]);
    const short* vss = (const short*)vs;
    #pragma unroll
    for (int dt = 0; dt < 4; dt++) {
      s16x8 vb0 = *(const s16x8*)(&vss[(dt * 16 + m16) * 72 + quad * 8]);
      s16x8 vb1 = *(const s16x8*)(&vss[(dt * 16 + m16) * 72 + 32 + quad * 8]);
      #pragma unroll
      for (int mt = 0; mt < 2; mt++) {
        oacc[mt][dt] = __builtin_amdgcn_mfma_f32_16x16x32_bf16(pa[mt][0], vb0, oacc[mt][dt], 0, 0, 0);
        oacc[mt][dt] = __builtin_amdgcn_mfma_f32_16x16x32_bf16(pa[mt][1], vb1, oacc[mt][dt], 0, 0, 0);
      }
    }
  }
  // ---- l: reduce across the 4 quad-lanes holding each q-row
  #pragma unroll
  for (int nt = 0; nt < 2; nt++) {
    float l = lp[nt];
    l += __shfl_xor(l, 16, 64);
    l += __shfl_xor(l, 32, 64);
    if (quad == 0) lsum[w * 32 + nt * 16 + m16] = l;
  }
  __syncthreads();
  // ---- normalize + store (O layout: row=quad*4+reg+mt*16, dim=dt*16+m16)
  #pragma unroll
  for (int mt = 0; mt < 2; mt++) {
    float rinv[4];
    #pragma unroll
    for (int r = 0; r < 4; r++) rinv[r] = 1.0f / lsum[w * 32 + mt * 16 + quad * 4 + r];
    #pragma unroll
    for (int dt = 0; dt < 4; dt++) {
      #pragma unroll
      for (int r = 0; r < 4; r++) {
        int grow = b * N_ + qbase + w * 32 + mt * 16 + quad * 4 + r;
        attn_out[(size_t)grow * D_ + h * 64 + dt * 16 + m16] = f2bf(oacc[mt][dt][r] * rinv[r]);
      }
    }
  }
}

// ---------------- launch ----------------
extern "C" void kernel_launch(void* const* d_in, const int* in_sizes, int n_in,
                              void* d_out, int out_size, void* d_ws, size_t ws_size,
                              hipStream_t stream) {
  (void)in_sizes; (void)n_in; (void)out_size; (void)ws_size;
  const float* x     = (const float*)d_in[0];
  const float* canny = (const float*)d_in[1];
  const float* noise = (const float*)d_in[2];
  const float* lnw   = (const float*)d_in[3];
  const float* lnb   = (const float*)d_in[4];
  const float* wqkv  = (const float*)d_in[5];
  const float* wout  = (const float*)d_in[6];
  const float* bout  = (const float*)d_in[7];
  float* out = (float*)d_out;
  char* ws = (char*)d_ws;

  unsigned short* xn    = (unsigned short*)(ws);              // 8320*768 bf16 (reused as attn_out)
  unsigned short* wqkvT = (unsigned short*)(ws + 12779520);   // 2304*768
  unsigned short* woutT = (unsigned short*)(ws + 16318464);   // 768*768
  unsigned short* qkv   = (unsigned short*)(ws + 17498112);   // 8200*2304

  transpose_f2b<<<dim3(QKVC_ / 32, D_ / 32), 256, 0, stream>>>(wqkv, wqkvT, D_, QKVC_);
  transpose_f2b<<<dim3(D_ / 32, D_ / 32), 256, 0, stream>>>(wout, woutT, D_, D_);
  layernorm_k<<<dim3(ROWS_), 256, 0, stream>>>(x, lnw, lnb, xn);
  gemm_bt<false><<<dim3(QKVC_ / 128, ROWS_PAD_ / 128), 256, 0, stream>>>(
      xn, wqkvT, (void*)qkv, nullptr, ROWS_, QKVC_, D_);
  attn_cls<<<dim3(B_ * H_), 256, 0, stream>>>(qkv, canny, noise, xn);
  attn_main<<<dim3(8, H_, B_), 256, 0, stream>>>(qkv, xn);
  gemm_bt<true><<<dim3(D_ / 128, ROWS_PAD_ / 128), 256, 0, stream>>>(
      xn, woutT, (void*)out, bout, ROWS_, D_, D_);
}

// Round 7
// 241.995 us; speedup vs baseline: 3.9206x; 1.0639x over previous
//
#include <hip/hip_runtime.h>

#define B_ 8
#define N_ 1025
#define D_ 768
#define H_ 12
#define NP_ 1024
#define ROWS_ (B_*N_)        /* 8200 */
#define ROWS_PAD_ 8320       /* 65*128 */
#define QKVC_ 2304
#define SCALE_ 0.03608439182435161f  /* 768^-0.5 */
#define EPS_ 1e-5f

typedef float f32x4 __attribute__((ext_vector_type(4)));
typedef short s16x8 __attribute__((ext_vector_type(8)));
typedef unsigned short u16x4 __attribute__((ext_vector_type(4)));

// async global->LDS, 16B per lane; lds dest must be wave-uniform base + lane*16
#define GLD16(g, l) __builtin_amdgcn_global_load_lds( \
    (const __attribute__((address_space(1))) unsigned int*)(g), \
    (__attribute__((address_space(3))) unsigned int*)(l), 16, 0, 0)

__device__ __forceinline__ float blo(unsigned int u){
  union { unsigned int i; float f; } v; v.i = u << 16; return v.f;
}
__device__ __forceinline__ float bhi(unsigned int u){
  union { unsigned int i; float f; } v; v.i = u & 0xffff0000u; return v.f;
}
__device__ __forceinline__ float bf2f(unsigned short u){
  union { unsigned int i; float f; } v; v.i = ((unsigned int)u) << 16; return v.f;
}
__device__ __forceinline__ unsigned short f2bf(float f){
  union { unsigned int i; float f; } v; v.f = f;
  unsigned int b = v.i;
  b = b + 0x7fffu + ((b >> 16) & 1u);
  return (unsigned short)(b >> 16);
}

// ---------------- transpose (K x N) fp32 -> (N x K) bf16 ----------------
__global__ __launch_bounds__(256) void transpose_f2b(
    const float* __restrict__ src, unsigned short* __restrict__ dst,
    int K, int N) {
  __shared__ unsigned short tile[32][33];
  int kb = blockIdx.y * 32, nb = blockIdx.x * 32;
  int tx = threadIdx.x & 31, ty = threadIdx.x >> 5;  // 32 x 8
  #pragma unroll
  for (int i = 0; i < 4; i++) {
    int r = ty + i * 8;
    tile[r][tx] = f2bf(src[(size_t)(kb + r) * N + nb + tx]);
  }
  __syncthreads();
  #pragma unroll
  for (int i = 0; i < 4; i++) {
    int r = ty + i * 8;
    dst[(size_t)(nb + r) * K + kb + tx] = tile[tx][r];
  }
}

// ---------------- layernorm: x[8200][768] fp32 -> xn bf16 ----------------
__global__ __launch_bounds__(256) void layernorm_k(
    const float* __restrict__ x, const float* __restrict__ w,
    const float* __restrict__ b, unsigned short* __restrict__ xn) {
  int row = blockIdx.x;
  int t = threadIdx.x;
  const float* xr = x + (size_t)row * D_;
  float v0 = xr[t], v1 = xr[t + 256], v2 = xr[t + 512];
  __shared__ float rs[256], rq[256];
  rs[t] = v0 + v1 + v2;
  rq[t] = v0 * v0 + v1 * v1 + v2 * v2;
  __syncthreads();
  for (int st = 128; st > 0; st >>= 1) {
    if (t < st) { rs[t] += rs[t + st]; rq[t] += rq[t + st]; }
    __syncthreads();
  }
  float mean = rs[0] * (1.0f / 768.0f);
  float var = rq[0] * (1.0f / 768.0f) - mean * mean;
  var = var < 0.f ? 0.f : var;
  float rstd = rsqrtf(var + EPS_);
  unsigned short* yr = xn + (size_t)row * D_;
  yr[t]       = f2bf((v0 - mean) * rstd * w[t]       + b[t]);
  yr[t + 256] = f2bf((v1 - mean) * rstd * w[t + 256] + b[t + 256]);
  yr[t + 512] = f2bf((v2 - mean) * rstd * w[t + 512] + b[t + 512]);
}

// ---------------- GEMM: C[M][N] = A[M][K] * Bt[N][K]^T (+bias)
// bf16 in, fp32 acc; output bf16 (OF32=false) or fp32+bias (OF32=true).
// 128x128 tile, BK=64 as two 128x32 K-half tiles, global_load_lds staging,
// coalesced LDS-staged epilogue (16B/lane stores).
template <bool OF32>
__global__ __launch_bounds__(256) void gemm_bt(
    const unsigned short* __restrict__ A, const unsigned short* __restrict__ Bt,
    void* __restrict__ Cv, const float* __restrict__ bias,
    int Mvalid, int Nn, int Kk) {
  __shared__ short sh[16384];  // As[2][4096] | Bs[2][4096]; reused as C-stage
  short (*As)[4096] = (short (*)[4096])sh;
  short (*Bs)[4096] = (short (*)[4096])(sh + 8192);
  int t = threadIdx.x;
  int bm = blockIdx.y * 128, bn = blockIdx.x * 128;
  int lane = t & 63, wave = t >> 6;
  int wm = (wave & 1) * 64, wn = (wave >> 1) * 64;
  int m16 = lane & 15, quad = lane >> 4;
  f32x4 acc[4][4];
  #pragma unroll
  for (int i = 0; i < 4; i++)
    #pragma unroll
    for (int j = 0; j < 4; j++) acc[i][j] = (f32x4){0.f, 0.f, 0.f, 0.f};

  // staging: thread t owns 16B chunks t and t+256 of each 8KB half-tile
  int e0 = t * 8;             // element offset of chunk t (8 shorts = 16B)
  int e1 = (t + 256) * 8;
  int r0 = e0 >> 5, c0 = e0 & 31;
  int r1 = e1 >> 5, c1 = e1 & 31;
  const unsigned short* a0p = A + (size_t)(bm + r0) * Kk + c0;
  const unsigned short* a1p = A + (size_t)(bm + r1) * Kk + c1;
  const unsigned short* b0p = Bt + (size_t)(bn + r0) * Kk + c0;
  const unsigned short* b1p = Bt + (size_t)(bn + r1) * Kk + c1;

  int ksteps = Kk >> 6;  // BK=64
  for (int kt = 0; kt < ksteps; kt++) {
    int k0 = kt * 64, k1 = kt * 64 + 32;
    __syncthreads();
    GLD16(a0p + k0, &As[0][e0]);
    GLD16(a1p + k0, &As[0][e1]);
    GLD16(a0p + k1, &As[1][e0]);
    GLD16(a1p + k1, &As[1][e1]);
    GLD16(b0p + k0, &Bs[0][e0]);
    GLD16(b1p + k0, &Bs[0][e1]);
    GLD16(b0p + k1, &Bs[1][e0]);
    GLD16(b1p + k1, &Bs[1][e1]);
    __syncthreads();
    #pragma unroll
    for (int hh = 0; hh < 2; hh++) {
      s16x8 af[4], bfr[4];
      #pragma unroll
      for (int i = 0; i < 4; i++) {
        af[i]  = *(const s16x8*)(&As[hh][(wm + i * 16 + m16) * 32 + quad * 8]);
        bfr[i] = *(const s16x8*)(&Bs[hh][(wn + i * 16 + m16) * 32 + quad * 8]);
      }
      #pragma unroll
      for (int i = 0; i < 4; i++)
        #pragma unroll
        for (int j = 0; j < 4; j++)
          acc[i][j] = __builtin_amdgcn_mfma_f32_16x16x32_bf16(af[i], bfr[j], acc[i][j], 0, 0, 0);
    }
  }
  // ---- epilogue: stage C through LDS, store 16B/lane coalesced
  if (!OF32) {
    unsigned short* C = (unsigned short*)Cv;
    __syncthreads();  // all fragment reads of As/Bs complete
    #pragma unroll
    for (int j = 0; j < 4; j++) {
      int col = wn + j * 16 + m16;
      #pragma unroll
      for (int i = 0; i < 4; i++)
        #pragma unroll
        for (int r = 0; r < 4; r++)
          sh[(wm + i * 16 + quad * 4 + r) * 128 + col] = (short)f2bf(acc[i][j][r]);
    }
    __syncthreads();
    #pragma unroll
    for (int c = 0; c < 8; c++) {
      int idx = c * 256 + t;
      int row = idx >> 4, col = (idx & 15) * 8;
      if (bm + row < Mvalid)
        *(uint4*)(&C[(size_t)(bm + row) * Nn + bn + col]) = *(const uint4*)(&sh[row * 128 + col]);
    }
  } else {
    float* Cf = (float*)Cv;
    float* shf = (float*)sh;  // 8192 floats = 128 x 64
    #pragma unroll
    for (int half = 0; half < 2; half++) {
      __syncthreads();  // (half 0) frag reads done / (half 1) prior reads done
      if ((wn >> 6) == half) {
        #pragma unroll
        for (int j = 0; j < 4; j++) {
          int col_l = wn + j * 16 + m16;
          float bv = bias ? bias[bn + col_l] : 0.f;
          #pragma unroll
          for (int i = 0; i < 4; i++)
            #pragma unroll
            for (int r = 0; r < 4; r++)
              shf[(wm + i * 16 + quad * 4 + r) * 64 + (col_l & 63)] = acc[i][j][r] + bv;
        }
      }
      __syncthreads();
      #pragma unroll
      for (int c = 0; c < 8; c++) {
        int idx = c * 256 + t;
        int row = idx >> 4, col = (idx & 15) * 4;
        if (bm + row < Mvalid)
          *(float4*)(&Cf[(size_t)(bm + row) * Nn + bn + half * 64 + col]) =
              *(const float4*)(&shf[row * 64 + col]);
      }
    }
  }
}

// ---------------- block-wide sum helper ----------------
__device__ __forceinline__ float block_sum(float v, float* red) {
  int t = threadIdx.x;
  red[t] = v;
  __syncthreads();
  for (int st = 128; st > 0; st >>= 1) {
    if (t < st) red[t] += red[t + st];
    __syncthreads();
  }
  float r = red[0];
  __syncthreads();
  return r;
}

// ---------------- CLS-row attention (row 0 of each (b,h)) ----------------
__global__ __launch_bounds__(256) void attn_cls(
    const unsigned short* __restrict__ qkv, const float* __restrict__ canny,
    const float* __restrict__ noise, unsigned short* __restrict__ attn_out) {
  int bh = blockIdx.x;
  int b = bh / H_, h = bh % H_;
  int t = threadIdx.x;
  __shared__ float s[N_];
  __shared__ float red[256];
  __shared__ float q[64];
  __shared__ float pvred[64 * 33];  // [dim][group], +1 pad -> conflict-free

  if (t < 64) q[t] = bf2f(qkv[(size_t)(b * N_) * QKVC_ + h * 64 + t]);
  __syncthreads();

  // QK: vectorized uint4 loads (8 x 16B per key row)
  for (int j = t; j < N_; j += 256) {
    const unsigned short* krow = qkv + (size_t)(b * N_ + j) * QKVC_ + D_ + h * 64;
    float dot = 0.f;
    #pragma unroll
    for (int c = 0; c < 8; c++) {
      uint4 kk = *(const uint4*)(krow + c * 8);
      dot += q[c*8+0]*blo(kk.x) + q[c*8+1]*bhi(kk.x)
           + q[c*8+2]*blo(kk.y) + q[c*8+3]*bhi(kk.y)
           + q[c*8+4]*blo(kk.z) + q[c*8+5]*bhi(kk.z)
           + q[c*8+6]*blo(kk.w) + q[c*8+7]*bhi(kk.w);
    }
    s[j] = dot * SCALE_;
  }
  float cp = 0.f, npp = 0.f;
  for (int j = t; j < NP_; j += 256) {
    cp  += canny[b * NP_ + j] + 1.0f;
    npp += noise[b * NP_ + j];
  }
  float csum = block_sum(cp, red);
  float nsum = block_sum(npp, red);
  float e1 = 0.f;
  for (int j = t; j < N_; j += 256) if (j >= 1) e1 += __expf(s[j]);
  float sum1 = block_sum(e1, red);
  for (int j = t; j < N_; j += 256) {
    if (j >= 1) {
      s[j] = __expf(s[j]) / sum1
           + (canny[b * NP_ + j - 1] + 1.0f) / csum
           + noise[b * NP_ + j - 1] / nsum;
    }
  }
  __syncthreads();
  float e2 = 0.f;
  for (int j = t; j < N_; j += 256) { float e = __expf(s[j]); s[j] = e; e2 += e; }
  float sum2 = block_sum(e2, red);
  // PV: thread owns dim-octet o (8 dims), strides 32 rows -> 1 uint4 load/iter
  {
    int o = t & 7, g = t >> 3;
    float a[8] = {0.f, 0.f, 0.f, 0.f, 0.f, 0.f, 0.f, 0.f};
    for (int j = g; j < N_; j += 32) {
      float sv = s[j];
      uint4 vv = *(const uint4*)(qkv + (size_t)(b * N_ + j) * QKVC_ + 2 * D_ + h * 64 + o * 8);
      a[0] += sv * blo(vv.x); a[1] += sv * bhi(vv.x);
      a[2] += sv * blo(vv.y); a[3] += sv * bhi(vv.y);
      a[4] += sv * blo(vv.z); a[5] += sv * bhi(vv.z);
      a[6] += sv * blo(vv.w); a[7] += sv * bhi(vv.w);
    }
    #pragma unroll
    for (int i = 0; i < 8; i++) pvred[(o * 8 + i) * 33 + g] = a[i];
  }
  __syncthreads();
  if (t < 64) {
    float acc = 0.f;
    #pragma unroll
    for (int u = 0; u < 32; u++) acc += pvred[t * 33 + u];
    attn_out[(size_t)(b * N_) * D_ + h * 64 + t] = f2bf(acc / sum2);
  }
}

// ---------------- main attention (MFMA): rows 1..1024, 128 rows/block ----------------
// S^T = K·Q^T via mfma (A=K[key][hd], B=Q[row][hd]) so each lane holds P for a
// fixed q-row (col=lane&15) and 4 consecutive keys (row=quad*4+reg) -> b64 P
// writes to LDS in PV A-operand layout. V^T staged per tile for the PV B-operand.
// 16 unmasked 64-key tiles (keys 0..1023) + scalar tail for key 1024.
__global__ __launch_bounds__(256) void attn_main(
    const unsigned short* __restrict__ qkv, unsigned short* __restrict__ attn_out) {
  int tile = blockIdx.x;  // 0..7 (128 q-rows each)
  int h = blockIdx.y;     // 0..11
  int b = blockIdx.z;     // 0..7
  int t = threadIdx.x;
  int lane = t & 63, w = t >> 6;
  int m16 = lane & 15, quad = lane >> 4;

  __shared__ short ps[128 * 72];        // Q staging, then P tiles [row][key]
  __shared__ short ks[64 * 72];         // K tile [key][hd]
  __shared__ unsigned int vs[64 * 36];  // V^T tile [dim][keypair]
  __shared__ float lsum[128];
  __shared__ float tailbuf[256];        // k1024[64] | v1024[64] | p[128]

  int qbase = 1 + tile * 128;

  // ---- stage Q (each wave stages exactly its own 32 rows: t>>1 in [32w,32w+31])
  {
    int r = t >> 1, seg = (t & 1) * 32;
    const uint4* src = (const uint4*)(qkv + (size_t)(b * N_ + qbase + r) * QKVC_ + h * 64 + seg);
    uint4 u0 = src[0], u1 = src[1], u2 = src[2], u3 = src[3];
    *(uint4*)(&ps[r * 72 + seg])      = u0;
    *(uint4*)(&ps[r * 72 + seg + 8])  = u1;
    *(uint4*)(&ps[r * 72 + seg + 16]) = u2;
    *(uint4*)(&ps[r * 72 + seg + 24]) = u3;
  }
  // ---- Q B-operand fragments (lane n=m16 -> q-row, k=hd quad*8+j), held in regs
  s16x8 qb[2][2];
  #pragma unroll
  for (int nt = 0; nt < 2; nt++)
    #pragma unroll
    for (int ks_ = 0; ks_ < 2; ks_++)
      qb[nt][ks_] = *(const s16x8*)(&ps[(w * 32 + nt * 16 + m16) * 72 + ks_ * 32 + quad * 8]);

  f32x4 oacc[2][4];
  #pragma unroll
  for (int mt = 0; mt < 2; mt++)
    #pragma unroll
    for (int dt = 0; dt < 4; dt++) oacc[mt][dt] = (f32x4){0.f, 0.f, 0.f, 0.f};
  float lp[2] = {0.f, 0.f};

  for (int jt = 0; jt < 16; jt++) {
    __syncthreads();  // prior QK(ks) + PV(vs) reads complete
    // ---- stage K tile [key][hd] (all keys valid: <= 1023)
    {
      int key = t >> 2, seg = (t & 3) * 16;
      int j = jt * 64 + key;
      const uint4* src = (const uint4*)(qkv + (size_t)(b * N_ + j) * QKVC_ + D_ + h * 64 + seg);
      uint4 k0 = src[0], k1 = src[1];
      *(uint4*)(&ks[key * 72 + seg])     = k0;
      *(uint4*)(&ks[key * 72 + seg + 8]) = k1;
    }
    // ---- stage V^T tile [dim][key] (packed keypairs)
    {
      int p2 = t & 31, seg = t >> 5;  // keypair, dim-segment(8 dims)
      int j0 = jt * 64 + 2 * p2, j1 = j0 + 1;
      uint4 va = *(const uint4*)(qkv + (size_t)(b * N_ + j0) * QKVC_ + 2 * D_ + h * 64 + seg * 8);
      uint4 vb = *(const uint4*)(qkv + (size_t)(b * N_ + j1) * QKVC_ + 2 * D_ + h * 64 + seg * 8);
      const unsigned short* pa_ = (const unsigned short*)&va;
      const unsigned short* pb_ = (const unsigned short*)&vb;
      #pragma unroll
      for (int i = 0; i < 8; i++)
        vs[(seg * 8 + i) * 36 + p2] = (unsigned int)pa_[i] | ((unsigned int)pb_[i] << 16);
    }
    __syncthreads();
    // ---- QK: S^T[key][qrow] per wave: 4 key-tiles x 2 row-tiles
    f32x4 sacc[4][2];
    #pragma unroll
    for (int kt = 0; kt < 4; kt++) {
      s16x8 ka0 = *(const s16x8*)(&ks[(kt * 16 + m16) * 72 + quad * 8]);
      s16x8 ka1 = *(const s16x8*)(&ks[(kt * 16 + m16) * 72 + 32 + quad * 8]);
      #pragma unroll
      for (int nt = 0; nt < 2; nt++) {
        f32x4 s = (f32x4){0.f, 0.f, 0.f, 0.f};
        s = __builtin_amdgcn_mfma_f32_16x16x32_bf16(ka0, qb[nt][0], s, 0, 0, 0);
        s = __builtin_amdgcn_mfma_f32_16x16x32_bf16(ka1, qb[nt][1], s, 0, 0, 0);
        sacc[kt][nt] = s;
      }
    }
    // ---- P = exp(S*scale); pack 4 consecutive keys -> b64 write (no masks)
    #pragma unroll
    for (int kt = 0; kt < 4; kt++) {
      #pragma unroll
      for (int nt = 0; nt < 2; nt++) {
        f32x4 s = sacc[kt][nt];
        float p0 = __expf(s[0] * SCALE_);
        float p1 = __expf(s[1] * SCALE_);
        float p2 = __expf(s[2] * SCALE_);
        float p3 = __expf(s[3] * SCALE_);
        lp[nt] += p0 + p1 + p2 + p3;
        u16x4 pk = {f2bf(p0), f2bf(p1), f2bf(p2), f2bf(p3)};
        *(u16x4*)(&ps[(w * 32 + nt * 16 + m16) * 72 + kt * 16 + quad * 4]) = pk;
      }
    }
    __syncthreads();
    // ---- PV: O[qrow][dim] += P·V
    s16x8 pa[2][2];
    #pragma unroll
    for (int mt = 0; mt < 2; mt++)
      #pragma unroll
      for (int ks_ = 0; ks_ < 2; ks_++)
        pa[mt][ks_] = *(const s16x8*)(&ps[(w * 32 + mt * 16 + m16) * 72 + ks_ * 32 + quad * 8]);
    const short* vss = (const short*)vs;
    #pragma unroll
    for (int dt = 0; dt < 4; dt++) {
      s16x8 vb0 = *(const s16x8*)(&vss[(dt * 16 + m16) * 72 + quad * 8]);
      s16x8 vb1 = *(const s16x8*)(&vss[(dt * 16 + m16) * 72 + 32 + quad * 8]);
      #pragma unroll
      for (int mt = 0; mt < 2; mt++) {
        oacc[mt][dt] = __builtin_amdgcn_mfma_f32_16x16x32_bf16(pa[mt][0], vb0, oacc[mt][dt], 0, 0, 0);
        oacc[mt][dt] = __builtin_amdgcn_mfma_f32_16x16x32_bf16(pa[mt][1], vb1, oacc[mt][dt], 0, 0, 0);
      }
    }
  }
  // ---- tail: key 1024 (scalar path via register-resident Q fragments)
  if (t < 64)       tailbuf[t]      = bf2f(qkv[(size_t)(b * N_ + 1024) * QKVC_ + D_     + h * 64 + t]);
  else if (t < 128) tailbuf[64 + (t - 64)] = bf2f(qkv[(size_t)(b * N_ + 1024) * QKVC_ + 2 * D_ + h * 64 + (t - 64)]);
  __syncthreads();
  #pragma unroll
  for (int nt = 0; nt < 2; nt++) {
    float d = 0.f;
    #pragma unroll
    for (int jj = 0; jj < 8; jj++) {
      d += bf2f((unsigned short)qb[nt][0][jj]) * tailbuf[quad * 8 + jj];
      d += bf2f((unsigned short)qb[nt][1][jj]) * tailbuf[32 + quad * 8 + jj];
    }
    d += __shfl_xor(d, 16, 64);
    d += __shfl_xor(d, 32, 64);
    float p = __expf(d * SCALE_);
    lp[nt] += p * 0.25f;  // counted 4x by the quad reduction below
    if (quad == 0) tailbuf[128 + w * 32 + nt * 16 + m16] = p;
  }
  __syncthreads();
  #pragma unroll
  for (int mt = 0; mt < 2; mt++)
    #pragma unroll
    for (int r = 0; r < 4; r++) {
      float pr = tailbuf[128 + w * 32 + mt * 16 + quad * 4 + r];
      #pragma unroll
      for (int dt = 0; dt < 4; dt++)
        oacc[mt][dt][r] += pr * tailbuf[64 + dt * 16 + m16];
    }
  // ---- l: reduce across the 4 quad-lanes holding each q-row
  #pragma unroll
  for (int nt = 0; nt < 2; nt++) {
    float l = lp[nt];
    l += __shfl_xor(l, 16, 64);
    l += __shfl_xor(l, 32, 64);
    if (quad == 0) lsum[w * 32 + nt * 16 + m16] = l;
  }
  __syncthreads();
  // ---- normalize + store (O layout: row=quad*4+reg+mt*16, dim=dt*16+m16)
  #pragma unroll
  for (int mt = 0; mt < 2; mt++) {
    float rinv[4];
    #pragma unroll
    for (int r = 0; r < 4; r++) rinv[r] = 1.0f / lsum[w * 32 + mt * 16 + quad * 4 + r];
    #pragma unroll
    for (int dt = 0; dt < 4; dt++) {
      #pragma unroll
      for (int r = 0; r < 4; r++) {
        int grow = b * N_ + qbase + w * 32 + mt * 16 + quad * 4 + r;
        attn_out[(size_t)grow * D_ + h * 64 + dt * 16 + m16] = f2bf(oacc[mt][dt][r] * rinv[r]);
      }
    }
  }
}

// ---------------- launch ----------------
extern "C" void kernel_launch(void* const* d_in, const int* in_sizes, int n_in,
                              void* d_out, int out_size, void* d_ws, size_t ws_size,
                              hipStream_t stream) {
  (void)in_sizes; (void)n_in; (void)out_size; (void)ws_size;
  const float* x     = (const float*)d_in[0];
  const float* canny = (const float*)d_in[1];
  const float* noise = (const float*)d_in[2];
  const float* lnw   = (const float*)d_in[3];
  const float* lnb   = (const float*)d_in[4];
  const float* wqkv  = (const float*)d_in[5];
  const float* wout  = (const float*)d_in[6];
  const float* bout  = (const float*)d_in[7];
  float* out = (float*)d_out;
  char* ws = (char*)d_ws;

  unsigned short* xn    = (unsigned short*)(ws);              // 8320*768 bf16 (reused as attn_out)
  unsigned short* wqkvT = (unsigned short*)(ws + 12779520);   // 2304*768
  unsigned short* woutT = (unsigned short*)(ws + 16318464);   // 768*768
  unsigned short* qkv   = (unsigned short*)(ws + 17498112);   // 8200*2304

  transpose_f2b<<<dim3(QKVC_ / 32, D_ / 32), 256, 0, stream>>>(wqkv, wqkvT, D_, QKVC_);
  transpose_f2b<<<dim3(D_ / 32, D_ / 32), 256, 0, stream>>>(wout, woutT, D_, D_);
  layernorm_k<<<dim3(ROWS_), 256, 0, stream>>>(x, lnw, lnb, xn);
  gemm_bt<false><<<dim3(QKVC_ / 128, ROWS_PAD_ / 128), 256, 0, stream>>>(
      xn, wqkvT, (void*)qkv, nullptr, ROWS_, QKVC_, D_);
  attn_cls<<<dim3(B_ * H_), 256, 0, stream>>>(qkv, canny, noise, xn);
  attn_main<<<dim3(8, H_, B_), 256, 0, stream>>>(qkv, xn);
  gemm_bt<true><<<dim3(D_ / 128, ROWS_PAD_ / 128), 256, 0, stream>>>(
      xn, woutT, (void*)out, bout, ROWS_, D_, D_);
}

// Round 8
// 236.827 us; speedup vs baseline: 4.0061x; 1.0218x over previous
//
#include <hip/hip_runtime.h>

#define B_ 8
#define N_ 1025
#define D_ 768
#define H_ 12
#define NP_ 1024
#define ROWS_ (B_*N_)        /* 8200 */
#define ROWS_PAD_ 8320       /* 65*128 */
#define QKVC_ 2304
#define SCALE_ 0.03608439182435161f  /* 768^-0.5 */
#define EPS_ 1e-5f

typedef float f32x4 __attribute__((ext_vector_type(4)));
typedef short s16x8 __attribute__((ext_vector_type(8)));
typedef unsigned short u16x4 __attribute__((ext_vector_type(4)));

// async global->LDS, 16B per lane; lds dest must be wave-uniform base + lane*16
#define GLD16(g, l) __builtin_amdgcn_global_load_lds( \
    (const __attribute__((address_space(1))) unsigned int*)(g), \
    (__attribute__((address_space(3))) unsigned int*)(l), 16, 0, 0)

__device__ __forceinline__ float blo(unsigned int u){
  union { unsigned int i; float f; } v; v.i = u << 16; return v.f;
}
__device__ __forceinline__ float bhi(unsigned int u){
  union { unsigned int i; float f; } v; v.i = u & 0xffff0000u; return v.f;
}
__device__ __forceinline__ float bf2f(unsigned short u){
  union { unsigned int i; float f; } v; v.i = ((unsigned int)u) << 16; return v.f;
}
__device__ __forceinline__ unsigned short f2bf(float f){
  union { unsigned int i; float f; } v; v.f = f;
  unsigned int b = v.i;
  b = b + 0x7fffu + ((b >> 16) & 1u);
  return (unsigned short)(b >> 16);
}
// pack two f32 -> two bf16 (round-half-up == RNE except exact ties) in 3 VALU ops
__device__ __forceinline__ unsigned int pkbf2(float a, float b){
  union { float f; unsigned int i; } ua, ub;
  ua.f = a; ub.f = b;
  return __builtin_amdgcn_perm(ub.i + 0x8000u, ua.i + 0x8000u, 0x07060302u);
}

// ---------------- transpose (K x N) fp32 -> (N x K) bf16 ----------------
__global__ __launch_bounds__(256) void transpose_f2b(
    const float* __restrict__ src, unsigned short* __restrict__ dst,
    int K, int N) {
  __shared__ unsigned short tile[32][33];
  int kb = blockIdx.y * 32, nb = blockIdx.x * 32;
  int tx = threadIdx.x & 31, ty = threadIdx.x >> 5;  // 32 x 8
  #pragma unroll
  for (int i = 0; i < 4; i++) {
    int r = ty + i * 8;
    tile[r][tx] = f2bf(src[(size_t)(kb + r) * N + nb + tx]);
  }
  __syncthreads();
  #pragma unroll
  for (int i = 0; i < 4; i++) {
    int r = ty + i * 8;
    dst[(size_t)(nb + r) * K + kb + tx] = tile[tx][r];
  }
}

// ---------------- layernorm: x[8200][768] fp32 -> xn bf16 ----------------
__global__ __launch_bounds__(256) void layernorm_k(
    const float* __restrict__ x, const float* __restrict__ w,
    const float* __restrict__ b, unsigned short* __restrict__ xn) {
  int row = blockIdx.x;
  int t = threadIdx.x;
  const float* xr = x + (size_t)row * D_;
  float v0 = xr[t], v1 = xr[t + 256], v2 = xr[t + 512];
  __shared__ float rs[256], rq[256];
  rs[t] = v0 + v1 + v2;
  rq[t] = v0 * v0 + v1 * v1 + v2 * v2;
  __syncthreads();
  for (int st = 128; st > 0; st >>= 1) {
    if (t < st) { rs[t] += rs[t + st]; rq[t] += rq[t + st]; }
    __syncthreads();
  }
  float mean = rs[0] * (1.0f / 768.0f);
  float var = rq[0] * (1.0f / 768.0f) - mean * mean;
  var = var < 0.f ? 0.f : var;
  float rstd = rsqrtf(var + EPS_);
  unsigned short* yr = xn + (size_t)row * D_;
  yr[t]       = f2bf((v0 - mean) * rstd * w[t]       + b[t]);
  yr[t + 256] = f2bf((v1 - mean) * rstd * w[t + 256] + b[t + 256]);
  yr[t + 512] = f2bf((v2 - mean) * rstd * w[t + 512] + b[t + 512]);
}

// ---------------- GEMM: C[M][N] = A[M][K] * Bt[N][K]^T (+bias)
// bf16 in, fp32 acc; output bf16 (OF32=false) or fp32+bias (OF32=true).
// 128x128 tile, BK=64 as two 128x32 K-half tiles, global_load_lds staging,
// coalesced LDS-staged epilogue (16B/lane stores).
template <bool OF32>
__global__ __launch_bounds__(256) void gemm_bt(
    const unsigned short* __restrict__ A, const unsigned short* __restrict__ Bt,
    void* __restrict__ Cv, const float* __restrict__ bias,
    int Mvalid, int Nn, int Kk) {
  __shared__ short sh[16384];  // As[2][4096] | Bs[2][4096]; reused as C-stage
  short (*As)[4096] = (short (*)[4096])sh;
  short (*Bs)[4096] = (short (*)[4096])(sh + 8192);
  int t = threadIdx.x;
  int bm = blockIdx.y * 128, bn = blockIdx.x * 128;
  int lane = t & 63, wave = t >> 6;
  int wm = (wave & 1) * 64, wn = (wave >> 1) * 64;
  int m16 = lane & 15, quad = lane >> 4;
  f32x4 acc[4][4];
  #pragma unroll
  for (int i = 0; i < 4; i++)
    #pragma unroll
    for (int j = 0; j < 4; j++) acc[i][j] = (f32x4){0.f, 0.f, 0.f, 0.f};

  // staging: thread t owns 16B chunks t and t+256 of each 8KB half-tile
  int e0 = t * 8;             // element offset of chunk t (8 shorts = 16B)
  int e1 = (t + 256) * 8;
  int r0 = e0 >> 5, c0 = e0 & 31;
  int r1 = e1 >> 5, c1 = e1 & 31;
  const unsigned short* a0p = A + (size_t)(bm + r0) * Kk + c0;
  const unsigned short* a1p = A + (size_t)(bm + r1) * Kk + c1;
  const unsigned short* b0p = Bt + (size_t)(bn + r0) * Kk + c0;
  const unsigned short* b1p = Bt + (size_t)(bn + r1) * Kk + c1;

  int ksteps = Kk >> 6;  // BK=64
  for (int kt = 0; kt < ksteps; kt++) {
    int k0 = kt * 64, k1 = kt * 64 + 32;
    __syncthreads();
    GLD16(a0p + k0, &As[0][e0]);
    GLD16(a1p + k0, &As[0][e1]);
    GLD16(a0p + k1, &As[1][e0]);
    GLD16(a1p + k1, &As[1][e1]);
    GLD16(b0p + k0, &Bs[0][e0]);
    GLD16(b1p + k0, &Bs[0][e1]);
    GLD16(b0p + k1, &Bs[1][e0]);
    GLD16(b1p + k1, &Bs[1][e1]);
    __syncthreads();
    #pragma unroll
    for (int hh = 0; hh < 2; hh++) {
      s16x8 af[4], bfr[4];
      #pragma unroll
      for (int i = 0; i < 4; i++) {
        af[i]  = *(const s16x8*)(&As[hh][(wm + i * 16 + m16) * 32 + quad * 8]);
        bfr[i] = *(const s16x8*)(&Bs[hh][(wn + i * 16 + m16) * 32 + quad * 8]);
      }
      #pragma unroll
      for (int i = 0; i < 4; i++)
        #pragma unroll
        for (int j = 0; j < 4; j++)
          acc[i][j] = __builtin_amdgcn_mfma_f32_16x16x32_bf16(af[i], bfr[j], acc[i][j], 0, 0, 0);
    }
  }
  // ---- epilogue: stage C through LDS, store 16B/lane coalesced
  if (!OF32) {
    unsigned short* C = (unsigned short*)Cv;
    __syncthreads();  // all fragment reads of As/Bs complete
    #pragma unroll
    for (int j = 0; j < 4; j++) {
      int col = wn + j * 16 + m16;
      #pragma unroll
      for (int i = 0; i < 4; i++)
        #pragma unroll
        for (int r = 0; r < 4; r++)
          sh[(wm + i * 16 + quad * 4 + r) * 128 + col] = (short)f2bf(acc[i][j][r]);
    }
    __syncthreads();
    #pragma unroll
    for (int c = 0; c < 8; c++) {
      int idx = c * 256 + t;
      int row = idx >> 4, col = (idx & 15) * 8;
      if (bm + row < Mvalid)
        *(uint4*)(&C[(size_t)(bm + row) * Nn + bn + col]) = *(const uint4*)(&sh[row * 128 + col]);
    }
  } else {
    float* Cf = (float*)Cv;
    float* shf = (float*)sh;  // 8192 floats = 128 x 64
    #pragma unroll
    for (int half = 0; half < 2; half++) {
      __syncthreads();  // (half 0) frag reads done / (half 1) prior reads done
      if ((wn >> 6) == half) {
        #pragma unroll
        for (int j = 0; j < 4; j++) {
          int col_l = wn + j * 16 + m16;
          float bv = bias ? bias[bn + col_l] : 0.f;
          #pragma unroll
          for (int i = 0; i < 4; i++)
            #pragma unroll
            for (int r = 0; r < 4; r++)
              shf[(wm + i * 16 + quad * 4 + r) * 64 + (col_l & 63)] = acc[i][j][r] + bv;
        }
      }
      __syncthreads();
      #pragma unroll
      for (int c = 0; c < 8; c++) {
        int idx = c * 256 + t;
        int row = idx >> 4, col = (idx & 15) * 4;
        if (bm + row < Mvalid)
          *(float4*)(&Cf[(size_t)(bm + row) * Nn + bn + half * 64 + col]) =
              *(const float4*)(&shf[row * 64 + col]);
      }
    }
  }
}

// ---------------- block-wide sum helper ----------------
__device__ __forceinline__ float block_sum(float v, float* red) {
  int t = threadIdx.x;
  red[t] = v;
  __syncthreads();
  for (int st = 128; st > 0; st >>= 1) {
    if (t < st) red[t] += red[t + st];
    __syncthreads();
  }
  float r = red[0];
  __syncthreads();
  return r;
}

// ---------------- CLS-row attention (row 0 of each (b,h)) ----------------
__global__ __launch_bounds__(256) void attn_cls(
    const unsigned short* __restrict__ qkv, const float* __restrict__ canny,
    const float* __restrict__ noise, unsigned short* __restrict__ attn_out) {
  int bh = blockIdx.x;
  int b = bh / H_, h = bh % H_;
  int t = threadIdx.x;
  __shared__ float s[N_];
  __shared__ float red[256];
  __shared__ float q[64];
  __shared__ float pvred[64 * 33];  // [dim][group], +1 pad -> conflict-free

  if (t < 64) q[t] = bf2f(qkv[(size_t)(b * N_) * QKVC_ + h * 64 + t]);
  __syncthreads();

  // QK: vectorized uint4 loads (8 x 16B per key row)
  for (int j = t; j < N_; j += 256) {
    const unsigned short* krow = qkv + (size_t)(b * N_ + j) * QKVC_ + D_ + h * 64;
    float dot = 0.f;
    #pragma unroll
    for (int c = 0; c < 8; c++) {
      uint4 kk = *(const uint4*)(krow + c * 8);
      dot += q[c*8+0]*blo(kk.x) + q[c*8+1]*bhi(kk.x)
           + q[c*8+2]*blo(kk.y) + q[c*8+3]*bhi(kk.y)
           + q[c*8+4]*blo(kk.z) + q[c*8+5]*bhi(kk.z)
           + q[c*8+6]*blo(kk.w) + q[c*8+7]*bhi(kk.w);
    }
    s[j] = dot * SCALE_;
  }
  float cp = 0.f, npp = 0.f;
  for (int j = t; j < NP_; j += 256) {
    cp  += canny[b * NP_ + j] + 1.0f;
    npp += noise[b * NP_ + j];
  }
  float csum = block_sum(cp, red);
  float nsum = block_sum(npp, red);
  float e1 = 0.f;
  for (int j = t; j < N_; j += 256) if (j >= 1) e1 += __expf(s[j]);
  float sum1 = block_sum(e1, red);
  for (int j = t; j < N_; j += 256) {
    if (j >= 1) {
      s[j] = __expf(s[j]) / sum1
           + (canny[b * NP_ + j - 1] + 1.0f) / csum
           + noise[b * NP_ + j - 1] / nsum;
    }
  }
  __syncthreads();
  float e2 = 0.f;
  for (int j = t; j < N_; j += 256) { float e = __expf(s[j]); s[j] = e; e2 += e; }
  float sum2 = block_sum(e2, red);
  // PV: thread owns dim-octet o (8 dims), strides 32 rows -> 1 uint4 load/iter
  {
    int o = t & 7, g = t >> 3;
    float a[8] = {0.f, 0.f, 0.f, 0.f, 0.f, 0.f, 0.f, 0.f};
    for (int j = g; j < N_; j += 32) {
      float sv = s[j];
      uint4 vv = *(const uint4*)(qkv + (size_t)(b * N_ + j) * QKVC_ + 2 * D_ + h * 64 + o * 8);
      a[0] += sv * blo(vv.x); a[1] += sv * bhi(vv.x);
      a[2] += sv * blo(vv.y); a[3] += sv * bhi(vv.y);
      a[4] += sv * blo(vv.z); a[5] += sv * bhi(vv.z);
      a[6] += sv * blo(vv.w); a[7] += sv * bhi(vv.w);
    }
    #pragma unroll
    for (int i = 0; i < 8; i++) pvred[(o * 8 + i) * 33 + g] = a[i];
  }
  __syncthreads();
  if (t < 64) {
    float acc = 0.f;
    #pragma unroll
    for (int u = 0; u < 32; u++) acc += pvred[t * 33 + u];
    attn_out[(size_t)(b * N_) * D_ + h * 64 + t] = f2bf(acc / sum2);
  }
}

// ---------------- main attention (MFMA): rows 1..1024, 128 rows/block ----------------
// S^T = K·Q^T via mfma (A=K[key][hd], B=Q[row][hd]) so each lane holds P for a
// fixed q-row (col=lane&15) and 4 consecutive keys (row=quad*4+reg) -> b64 P
// writes to LDS in PV A-operand layout. V^T staged per tile for the PV B-operand.
// 16 unmasked 64-key tiles (keys 0..1023) + scalar tail for key 1024.
// 1D grid with XCD swizzle: id = tile*96 + h*8 + b  =>  id%8 == b, so all 96
// blocks of batch b share one XCD's L2 (K+V for 12 heads = 3.1 MB < 4 MB).
__global__ __launch_bounds__(256) void attn_main(
    const unsigned short* __restrict__ qkv, unsigned short* __restrict__ attn_out) {
  int id = blockIdx.x;
  int tile = id / 96;
  int rem = id % 96;
  int h = rem >> 3;
  int b = rem & 7;
  int t = threadIdx.x;
  int lane = t & 63, w = t >> 6;
  int m16 = lane & 15, quad = lane >> 4;

  __shared__ short ps[128 * 72];        // Q staging, then P tiles [row][key]
  __shared__ short ks[64 * 72];         // K tile [key][hd]
  __shared__ unsigned int vs[64 * 36];  // V^T tile [dim][keypair]
  __shared__ float lsum[128];
  __shared__ float tailbuf[256];        // k1024[64] | v1024[64] | p[128]

  int qbase = 1 + tile * 128;

  // ---- stage Q (each wave stages exactly its own 32 rows: t>>1 in [32w,32w+31])
  {
    int r = t >> 1, seg = (t & 1) * 32;
    const uint4* src = (const uint4*)(qkv + (size_t)(b * N_ + qbase + r) * QKVC_ + h * 64 + seg);
    uint4 u0 = src[0], u1 = src[1], u2 = src[2], u3 = src[3];
    *(uint4*)(&ps[r * 72 + seg])      = u0;
    *(uint4*)(&ps[r * 72 + seg + 8])  = u1;
    *(uint4*)(&ps[r * 72 + seg + 16]) = u2;
    *(uint4*)(&ps[r * 72 + seg + 24]) = u3;
  }
  // ---- Q B-operand fragments (lane n=m16 -> q-row, k=hd quad*8+j), held in regs
  s16x8 qb[2][2];
  #pragma unroll
  for (int nt = 0; nt < 2; nt++)
    #pragma unroll
    for (int ks_ = 0; ks_ < 2; ks_++)
      qb[nt][ks_] = *(const s16x8*)(&ps[(w * 32 + nt * 16 + m16) * 72 + ks_ * 32 + quad * 8]);

  f32x4 oacc[2][4];
  #pragma unroll
  for (int mt = 0; mt < 2; mt++)
    #pragma unroll
    for (int dt = 0; dt < 4; dt++) oacc[mt][dt] = (f32x4){0.f, 0.f, 0.f, 0.f};
  float lp[2] = {0.f, 0.f};

  for (int jt = 0; jt < 16; jt++) {
    __syncthreads();  // prior QK(ks) + PV(vs) reads complete
    // ---- stage K tile [key][hd] (all keys valid: <= 1023)
    {
      int key = t >> 2, seg = (t & 3) * 16;
      int j = jt * 64 + key;
      const uint4* src = (const uint4*)(qkv + (size_t)(b * N_ + j) * QKVC_ + D_ + h * 64 + seg);
      uint4 k0 = src[0], k1 = src[1];
      *(uint4*)(&ks[key * 72 + seg])     = k0;
      *(uint4*)(&ks[key * 72 + seg + 8]) = k1;
    }
    // ---- stage V^T tile [dim][key] (packed keypairs, v_perm pack)
    {
      int p2 = t & 31, seg = t >> 5;  // keypair, dim-segment(8 dims)
      int j0 = jt * 64 + 2 * p2, j1 = j0 + 1;
      uint4 va = *(const uint4*)(qkv + (size_t)(b * N_ + j0) * QKVC_ + 2 * D_ + h * 64 + seg * 8);
      uint4 vb = *(const uint4*)(qkv + (size_t)(b * N_ + j1) * QKVC_ + 2 * D_ + h * 64 + seg * 8);
      const unsigned int* vaw = (const unsigned int*)&va;
      const unsigned int* vbw = (const unsigned int*)&vb;
      #pragma unroll
      for (int i = 0; i < 4; i++) {
        vs[(seg * 8 + 2 * i)     * 36 + p2] = __builtin_amdgcn_perm(vbw[i], vaw[i], 0x05040100u);
        vs[(seg * 8 + 2 * i + 1) * 36 + p2] = __builtin_amdgcn_perm(vbw[i], vaw[i], 0x07060302u);
      }
    }
    __syncthreads();
    // ---- QK: S^T[key][qrow] per wave: 4 key-tiles x 2 row-tiles
    f32x4 sacc[4][2];
    #pragma unroll
    for (int kt = 0; kt < 4; kt++) {
      s16x8 ka0 = *(const s16x8*)(&ks[(kt * 16 + m16) * 72 + quad * 8]);
      s16x8 ka1 = *(const s16x8*)(&ks[(kt * 16 + m16) * 72 + 32 + quad * 8]);
      #pragma unroll
      for (int nt = 0; nt < 2; nt++) {
        f32x4 s = (f32x4){0.f, 0.f, 0.f, 0.f};
        s = __builtin_amdgcn_mfma_f32_16x16x32_bf16(ka0, qb[nt][0], s, 0, 0, 0);
        s = __builtin_amdgcn_mfma_f32_16x16x32_bf16(ka1, qb[nt][1], s, 0, 0, 0);
        sacc[kt][nt] = s;
      }
    }
    // ---- P = exp(S*scale); v_perm pack 4 consecutive keys -> b64 write
    #pragma unroll
    for (int kt = 0; kt < 4; kt++) {
      #pragma unroll
      for (int nt = 0; nt < 2; nt++) {
        f32x4 s = sacc[kt][nt];
        float p0 = __expf(s[0] * SCALE_);
        float p1 = __expf(s[1] * SCALE_);
        float p2 = __expf(s[2] * SCALE_);
        float p3 = __expf(s[3] * SCALE_);
        lp[nt] += p0 + p1 + p2 + p3;
        uint2 pk = {pkbf2(p0, p1), pkbf2(p2, p3)};
        *(uint2*)(&ps[(w * 32 + nt * 16 + m16) * 72 + kt * 16 + quad * 4]) = pk;
      }
    }
    __syncthreads();
    // ---- PV: O[qrow][dim] += P·V
    s16x8 pa[2][2];
    #pragma unroll
    for (int mt = 0; mt < 2; mt++)
      #pragma unroll
      for (int ks_ = 0; ks_ < 2; ks_++)
        pa[mt][ks_] = *(const s16x8*)(&ps[(w * 32 + mt * 16 + m16) * 72 + ks_ * 32 + quad * 8]);
    const short* vss = (const short*)vs;
    #pragma unroll
    for (int dt = 0; dt < 4; dt++) {
      s16x8 vb0 = *(const s16x8*)(&vss[(dt * 16 + m16) * 72 + quad * 8]);
      s16x8 vb1 = *(const s16x8*)(&vss[(dt * 16 + m16) * 72 + 32 + quad * 8]);
      #pragma unroll
      for (int mt = 0; mt < 2; mt++) {
        oacc[mt][dt] = __builtin_amdgcn_mfma_f32_16x16x32_bf16(pa[mt][0], vb0, oacc[mt][dt], 0, 0, 0);
        oacc[mt][dt] = __builtin_amdgcn_mfma_f32_16x16x32_bf16(pa[mt][1], vb1, oacc[mt][dt], 0, 0, 0);
      }
    }
  }
  // ---- tail: key 1024 (scalar path via register-resident Q fragments)
  if (t < 64)       tailbuf[t]      = bf2f(qkv[(size_t)(b * N_ + 1024) * QKVC_ + D_     + h * 64 + t]);
  else if (t < 128) tailbuf[64 + (t - 64)] = bf2f(qkv[(size_t)(b * N_ + 1024) * QKVC_ + 2 * D_ + h * 64 + (t - 64)]);
  __syncthreads();
  #pragma unroll
  for (int nt = 0; nt < 2; nt++) {
    float d = 0.f;
    #pragma unroll
    for (int jj = 0; jj < 8; jj++) {
      d += bf2f((unsigned short)qb[nt][0][jj]) * tailbuf[quad * 8 + jj];
      d += bf2f((unsigned short)qb[nt][1][jj]) * tailbuf[32 + quad * 8 + jj];
    }
    d += __shfl_xor(d, 16, 64);
    d += __shfl_xor(d, 32, 64);
    float p = __expf(d * SCALE_);
    lp[nt] += p * 0.25f;  // counted 4x by the quad reduction below
    if (quad == 0) tailbuf[128 + w * 32 + nt * 16 + m16] = p;
  }
  __syncthreads();
  #pragma unroll
  for (int mt = 0; mt < 2; mt++)
    #pragma unroll
    for (int r = 0; r < 4; r++) {
      float pr = tailbuf[128 + w * 32 + mt * 16 + quad * 4 + r];
      #pragma unroll
      for (int dt = 0; dt < 4; dt++)
        oacc[mt][dt][r] += pr * tailbuf[64 + dt * 16 + m16];
    }
  // ---- l: reduce across the 4 quad-lanes holding each q-row
  #pragma unroll
  for (int nt = 0; nt < 2; nt++) {
    float l = lp[nt];
    l += __shfl_xor(l, 16, 64);
    l += __shfl_xor(l, 32, 64);
    if (quad == 0) lsum[w * 32 + nt * 16 + m16] = l;
  }
  __syncthreads();
  // ---- normalize + store (O layout: row=quad*4+reg+mt*16, dim=dt*16+m16)
  #pragma unroll
  for (int mt = 0; mt < 2; mt++) {
    float rinv[4];
    #pragma unroll
    for (int r = 0; r < 4; r++) rinv[r] = 1.0f / lsum[w * 32 + mt * 16 + quad * 4 + r];
    #pragma unroll
    for (int dt = 0; dt < 4; dt++) {
      #pragma unroll
      for (int r = 0; r < 4; r++) {
        int grow = b * N_ + qbase + w * 32 + mt * 16 + quad * 4 + r;
        attn_out[(size_t)grow * D_ + h * 64 + dt * 16 + m16] = f2bf(oacc[mt][dt][r] * rinv[r]);
      }
    }
  }
}

// ---------------- launch ----------------
extern "C" void kernel_launch(void* const* d_in, const int* in_sizes, int n_in,
                              void* d_out, int out_size, void* d_ws, size_t ws_size,
                              hipStream_t stream) {
  (void)in_sizes; (void)n_in; (void)out_size; (void)ws_size;
  const float* x     = (const float*)d_in[0];
  const float* canny = (const float*)d_in[1];
  const float* noise = (const float*)d_in[2];
  const float* lnw   = (const float*)d_in[3];
  const float* lnb   = (const float*)d_in[4];
  const float* wqkv  = (const float*)d_in[5];
  const float* wout  = (const float*)d_in[6];
  const float* bout  = (const float*)d_in[7];
  float* out = (float*)d_out;
  char* ws = (char*)d_ws;

  unsigned short* xn    = (unsigned short*)(ws);              // 8320*768 bf16 (reused as attn_out)
  unsigned short* wqkvT = (unsigned short*)(ws + 12779520);   // 2304*768
  unsigned short* woutT = (unsigned short*)(ws + 16318464);   // 768*768
  unsigned short* qkv   = (unsigned short*)(ws + 17498112);   // 8200*2304

  transpose_f2b<<<dim3(QKVC_ / 32, D_ / 32), 256, 0, stream>>>(wqkv, wqkvT, D_, QKVC_);
  transpose_f2b<<<dim3(D_ / 32, D_ / 32), 256, 0, stream>>>(wout, woutT, D_, D_);
  layernorm_k<<<dim3(ROWS_), 256, 0, stream>>>(x, lnw, lnb, xn);
  gemm_bt<false><<<dim3(QKVC_ / 128, ROWS_PAD_ / 128), 256, 0, stream>>>(
      xn, wqkvT, (void*)qkv, nullptr, ROWS_, QKVC_, D_);
  attn_cls<<<dim3(B_ * H_), 256, 0, stream>>>(qkv, canny, noise, xn);
  attn_main<<<dim3(8 * H_ * B_), 256, 0, stream>>>(qkv, xn);
  gemm_bt<true><<<dim3(D_ / 128, ROWS_PAD_ / 128), 256, 0, stream>>>(
      xn, woutT, (void*)out, bout, ROWS_, D_, D_);
}

// Round 9
// 224.690 us; speedup vs baseline: 4.2225x; 1.0540x over previous
//
#include <hip/hip_runtime.h>

#define B_ 8
#define N_ 1025
#define D_ 768
#define H_ 12
#define NP_ 1024
#define ROWS_ (B_*N_)        /* 8200 */
#define ROWS_PAD_ 8320       /* 65*128 */
#define QKVC_ 2304
#define SCALE_ 0.03608439182435161f  /* 768^-0.5 */
#define EPS_ 1e-5f

typedef float f32x4 __attribute__((ext_vector_type(4)));
typedef short s16x8 __attribute__((ext_vector_type(8)));

// async global->LDS, 16B per lane; lds dest must be wave-uniform base + lane*16
#define GLD16(g, l) __builtin_amdgcn_global_load_lds( \
    (const __attribute__((address_space(1))) unsigned int*)(g), \
    (__attribute__((address_space(3))) unsigned int*)(l), 16, 0, 0)

__device__ __forceinline__ float blo(unsigned int u){
  union { unsigned int i; float f; } v; v.i = u << 16; return v.f;
}
__device__ __forceinline__ float bhi(unsigned int u){
  union { unsigned int i; float f; } v; v.i = u & 0xffff0000u; return v.f;
}
__device__ __forceinline__ float bf2f(unsigned short u){
  union { unsigned int i; float f; } v; v.i = ((unsigned int)u) << 16; return v.f;
}
__device__ __forceinline__ unsigned short f2bf(float f){
  union { unsigned int i; float f; } v; v.f = f;
  unsigned int b = v.i;
  b = b + 0x7fffu + ((b >> 16) & 1u);
  return (unsigned short)(b >> 16);
}
// pack two f32 -> two bf16 (round-half-up == RNE except exact ties) in 3 VALU ops
__device__ __forceinline__ unsigned int pkbf2(float a, float b){
  union { float f; unsigned int i; } ua, ub;
  ua.f = a; ub.f = b;
  return __builtin_amdgcn_perm(ub.i + 0x8000u, ua.i + 0x8000u, 0x07060302u);
}

// ---------------- fused weight transposes (768 x N) fp32 -> (N x 768) bf16 ----
__global__ __launch_bounds__(256) void transpose_f2b2(
    const float* __restrict__ w1, unsigned short* __restrict__ d1,
    const float* __restrict__ w2, unsigned short* __restrict__ d2) {
  __shared__ unsigned short tile[32][33];
  int bx = blockIdx.x;
  const float* src; unsigned short* dst; int N, nb;
  if (bx < 72) { src = w1; dst = d1; N = QKVC_; nb = bx * 32; }
  else         { src = w2; dst = d2; N = D_;    nb = (bx - 72) * 32; }
  int kb = blockIdx.y * 32;
  int tx = threadIdx.x & 31, ty = threadIdx.x >> 5;  // 32 x 8
  #pragma unroll
  for (int i = 0; i < 4; i++) {
    int r = ty + i * 8;
    tile[r][tx] = f2bf(src[(size_t)(kb + r) * N + nb + tx]);
  }
  __syncthreads();
  #pragma unroll
  for (int i = 0; i < 4; i++) {
    int r = ty + i * 8;
    dst[(size_t)(nb + r) * D_ + kb + tx] = tile[tx][r];
  }
}

// ---------------- layernorm: x[8200][768] fp32 -> xn bf16 (shuffle-reduce) ----
__global__ __launch_bounds__(256) void layernorm_k(
    const float* __restrict__ x, const float* __restrict__ w,
    const float* __restrict__ b, unsigned short* __restrict__ xn) {
  int row = blockIdx.x;
  int t = threadIdx.x;
  const float* xr = x + (size_t)row * D_;
  float v0 = xr[t], v1 = xr[t + 256], v2 = xr[t + 512];
  float s = v0 + v1 + v2;
  float q = v0 * v0 + v1 * v1 + v2 * v2;
  #pragma unroll
  for (int off = 32; off > 0; off >>= 1) {
    s += __shfl_xor(s, off, 64);
    q += __shfl_xor(q, off, 64);
  }
  __shared__ float r8[8];
  int wv = t >> 6;
  if ((t & 63) == 0) { r8[wv] = s; r8[4 + wv] = q; }
  __syncthreads();
  s = r8[0] + r8[1] + r8[2] + r8[3];
  q = r8[4] + r8[5] + r8[6] + r8[7];
  float mean = s * (1.0f / 768.0f);
  float var = q * (1.0f / 768.0f) - mean * mean;
  var = var < 0.f ? 0.f : var;
  float rstd = rsqrtf(var + EPS_);
  unsigned short* yr = xn + (size_t)row * D_;
  yr[t]       = f2bf((v0 - mean) * rstd * w[t]       + b[t]);
  yr[t + 256] = f2bf((v1 - mean) * rstd * w[t + 256] + b[t + 256]);
  yr[t + 512] = f2bf((v2 - mean) * rstd * w[t + 512] + b[t + 512]);
}

// ---------------- GEMM: C[M][N] = A[M][K] * Bt[N][K]^T (+bias)
// bf16 in, fp32 acc; output bf16 (OF32=false) or fp32+bias (OF32=true).
// 128x128 tile, BK=64 as two 128x32 K-half tiles, global_load_lds staging,
// coalesced LDS-staged epilogue (16B/lane stores).
template <bool OF32>
__global__ __launch_bounds__(256) void gemm_bt(
    const unsigned short* __restrict__ A, const unsigned short* __restrict__ Bt,
    void* __restrict__ Cv, const float* __restrict__ bias,
    int Mvalid, int Nn, int Kk) {
  __shared__ short sh[16384];  // As[2][4096] | Bs[2][4096]; reused as C-stage
  short (*As)[4096] = (short (*)[4096])sh;
  short (*Bs)[4096] = (short (*)[4096])(sh + 8192);
  int t = threadIdx.x;
  int bm = blockIdx.y * 128, bn = blockIdx.x * 128;
  int lane = t & 63, wave = t >> 6;
  int wm = (wave & 1) * 64, wn = (wave >> 1) * 64;
  int m16 = lane & 15, quad = lane >> 4;
  f32x4 acc[4][4];
  #pragma unroll
  for (int i = 0; i < 4; i++)
    #pragma unroll
    for (int j = 0; j < 4; j++) acc[i][j] = (f32x4){0.f, 0.f, 0.f, 0.f};

  // staging: thread t owns 16B chunks t and t+256 of each 8KB half-tile
  int e0 = t * 8;             // element offset of chunk t (8 shorts = 16B)
  int e1 = (t + 256) * 8;
  int r0 = e0 >> 5, c0 = e0 & 31;
  int r1 = e1 >> 5, c1 = e1 & 31;
  const unsigned short* a0p = A + (size_t)(bm + r0) * Kk + c0;
  const unsigned short* a1p = A + (size_t)(bm + r1) * Kk + c1;
  const unsigned short* b0p = Bt + (size_t)(bn + r0) * Kk + c0;
  const unsigned short* b1p = Bt + (size_t)(bn + r1) * Kk + c1;

  int ksteps = Kk >> 6;  // BK=64
  for (int kt = 0; kt < ksteps; kt++) {
    int k0 = kt * 64, k1 = kt * 64 + 32;
    __syncthreads();
    GLD16(a0p + k0, &As[0][e0]);
    GLD16(a1p + k0, &As[0][e1]);
    GLD16(a0p + k1, &As[1][e0]);
    GLD16(a1p + k1, &As[1][e1]);
    GLD16(b0p + k0, &Bs[0][e0]);
    GLD16(b1p + k0, &Bs[0][e1]);
    GLD16(b0p + k1, &Bs[1][e0]);
    GLD16(b1p + k1, &Bs[1][e1]);
    __syncthreads();
    #pragma unroll
    for (int hh = 0; hh < 2; hh++) {
      s16x8 af[4], bfr[4];
      #pragma unroll
      for (int i = 0; i < 4; i++) {
        af[i]  = *(const s16x8*)(&As[hh][(wm + i * 16 + m16) * 32 + quad * 8]);
        bfr[i] = *(const s16x8*)(&Bs[hh][(wn + i * 16 + m16) * 32 + quad * 8]);
      }
      #pragma unroll
      for (int i = 0; i < 4; i++)
        #pragma unroll
        for (int j = 0; j < 4; j++)
          acc[i][j] = __builtin_amdgcn_mfma_f32_16x16x32_bf16(af[i], bfr[j], acc[i][j], 0, 0, 0);
    }
  }
  // ---- epilogue: stage C through LDS, store 16B/lane coalesced
  if (!OF32) {
    unsigned short* C = (unsigned short*)Cv;
    __syncthreads();  // all fragment reads of As/Bs complete
    #pragma unroll
    for (int j = 0; j < 4; j++) {
      int col = wn + j * 16 + m16;
      #pragma unroll
      for (int i = 0; i < 4; i++)
        #pragma unroll
        for (int r = 0; r < 4; r++)
          sh[(wm + i * 16 + quad * 4 + r) * 128 + col] = (short)f2bf(acc[i][j][r]);
    }
    __syncthreads();
    #pragma unroll
    for (int c = 0; c < 8; c++) {
      int idx = c * 256 + t;
      int row = idx >> 4, col = (idx & 15) * 8;
      if (bm + row < Mvalid)
        *(uint4*)(&C[(size_t)(bm + row) * Nn + bn + col]) = *(const uint4*)(&sh[row * 128 + col]);
    }
  } else {
    float* Cf = (float*)Cv;
    float* shf = (float*)sh;  // 8192 floats = 128 x 64
    #pragma unroll
    for (int half = 0; half < 2; half++) {
      __syncthreads();  // (half 0) frag reads done / (half 1) prior reads done
      if ((wn >> 6) == half) {
        #pragma unroll
        for (int j = 0; j < 4; j++) {
          int col_l = wn + j * 16 + m16;
          float bv = bias ? bias[bn + col_l] : 0.f;
          #pragma unroll
          for (int i = 0; i < 4; i++)
            #pragma unroll
            for (int r = 0; r < 4; r++)
              shf[(wm + i * 16 + quad * 4 + r) * 64 + (col_l & 63)] = acc[i][j][r] + bv;
        }
      }
      __syncthreads();
      #pragma unroll
      for (int c = 0; c < 8; c++) {
        int idx = c * 256 + t;
        int row = idx >> 4, col = (idx & 15) * 4;
        if (bm + row < Mvalid)
          *(float4*)(&Cf[(size_t)(bm + row) * Nn + bn + half * 64 + col]) =
              *(const float4*)(&shf[row * 64 + col]);
      }
    }
  }
}

// ---------------- block-wide sum helper ----------------
__device__ __forceinline__ float block_sum(float v, float* red) {
  int t = threadIdx.x;
  red[t] = v;
  __syncthreads();
  for (int st = 128; st > 0; st >>= 1) {
    if (t < st) red[t] += red[t + st];
    __syncthreads();
  }
  float r = red[0];
  __syncthreads();
  return r;
}

// ---------------- CLS-row attention (row 0 of each (b,h)) ----------------
__global__ __launch_bounds__(256) void attn_cls(
    const unsigned short* __restrict__ qkv, const float* __restrict__ canny,
    const float* __restrict__ noise, unsigned short* __restrict__ attn_out) {
  int bh = blockIdx.x;
  int b = bh / H_, h = bh % H_;
  int t = threadIdx.x;
  __shared__ float s[N_];
  __shared__ float red[256];
  __shared__ float q[64];
  __shared__ float pvred[64 * 33];  // [dim][group], +1 pad -> conflict-free

  if (t < 64) q[t] = bf2f(qkv[(size_t)(b * N_) * QKVC_ + h * 64 + t]);
  __syncthreads();

  // QK: vectorized uint4 loads (8 x 16B per key row)
  for (int j = t; j < N_; j += 256) {
    const unsigned short* krow = qkv + (size_t)(b * N_ + j) * QKVC_ + D_ + h * 64;
    float dot = 0.f;
    #pragma unroll
    for (int c = 0; c < 8; c++) {
      uint4 kk = *(const uint4*)(krow + c * 8);
      dot += q[c*8+0]*blo(kk.x) + q[c*8+1]*bhi(kk.x)
           + q[c*8+2]*blo(kk.y) + q[c*8+3]*bhi(kk.y)
           + q[c*8+4]*blo(kk.z) + q[c*8+5]*bhi(kk.z)
           + q[c*8+6]*blo(kk.w) + q[c*8+7]*bhi(kk.w);
    }
    s[j] = dot * SCALE_;
  }
  float cp = 0.f, npp = 0.f;
  for (int j = t; j < NP_; j += 256) {
    cp  += canny[b * NP_ + j] + 1.0f;
    npp += noise[b * NP_ + j];
  }
  float csum = block_sum(cp, red);
  float nsum = block_sum(npp, red);
  float e1 = 0.f;
  for (int j = t; j < N_; j += 256) if (j >= 1) e1 += __expf(s[j]);
  float sum1 = block_sum(e1, red);
  for (int j = t; j < N_; j += 256) {
    if (j >= 1) {
      s[j] = __expf(s[j]) / sum1
           + (canny[b * NP_ + j - 1] + 1.0f) / csum
           + noise[b * NP_ + j - 1] / nsum;
    }
  }
  __syncthreads();
  float e2 = 0.f;
  for (int j = t; j < N_; j += 256) { float e = __expf(s[j]); s[j] = e; e2 += e; }
  float sum2 = block_sum(e2, red);
  // PV: thread owns dim-octet o (8 dims), strides 32 rows -> 1 uint4 load/iter
  {
    int o = t & 7, g = t >> 3;
    float a[8] = {0.f, 0.f, 0.f, 0.f, 0.f, 0.f, 0.f, 0.f};
    for (int j = g; j < N_; j += 32) {
      float sv = s[j];
      uint4 vv = *(const uint4*)(qkv + (size_t)(b * N_ + j) * QKVC_ + 2 * D_ + h * 64 + o * 8);
      a[0] += sv * blo(vv.x); a[1] += sv * bhi(vv.x);
      a[2] += sv * blo(vv.y); a[3] += sv * bhi(vv.y);
      a[4] += sv * blo(vv.z); a[5] += sv * bhi(vv.z);
      a[6] += sv * blo(vv.w); a[7] += sv * bhi(vv.w);
    }
    #pragma unroll
    for (int i = 0; i < 8; i++) pvred[(o * 8 + i) * 33 + g] = a[i];
  }
  __syncthreads();
  if (t < 64) {
    float acc = 0.f;
    #pragma unroll
    for (int u = 0; u < 32; u++) acc += pvred[t * 33 + u];
    attn_out[(size_t)(b * N_) * D_ + h * 64 + t] = f2bf(acc / sum2);
  }
}

// ---------------- main attention (MFMA): rows 1..1024, 128 rows/block ----------------
// S^T = K·Q^T via mfma; P exits in PV A-layout via b64 LDS writes; V^T staged
// per tile. SCALE pre-folded into Q fragments. l computed via ones-MFMA (lands
// in C-layout beside oacc). K/V register-prefetched one tile ahead (loads
// overlap QK+exp; drained at the P barrier). 16 unmasked tiles + key-1024 tail.
// XCD swizzle: id%8==b keeps each batch's K/V on one XCD's L2.
__global__ __launch_bounds__(256) void attn_main(
    const unsigned short* __restrict__ qkv, unsigned short* __restrict__ attn_out) {
  int id = blockIdx.x;
  int tile = id / 96;
  int rem = id % 96;
  int h = rem >> 3;
  int b = rem & 7;
  int t = threadIdx.x;
  int lane = t & 63, w = t >> 6;
  int m16 = lane & 15, quad = lane >> 4;

  __shared__ short ps[128 * 72];        // Q staging, then P tiles [row][key]
  __shared__ short ks[64 * 72];         // K tile [key][hd]
  __shared__ unsigned int vs[64 * 36];  // V^T tile [dim][keypair]
  __shared__ float tailbuf[256];        // k1024[64] | v1024[64] | p[128]

  int qbase = 1 + tile * 128;

  // ---- stage Q (each wave stages exactly its own 32 rows)
  {
    int r = t >> 1, seg = (t & 1) * 32;
    const uint4* src = (const uint4*)(qkv + (size_t)(b * N_ + qbase + r) * QKVC_ + h * 64 + seg);
    uint4 u0 = src[0], u1 = src[1], u2 = src[2], u3 = src[3];
    *(uint4*)(&ps[r * 72 + seg])      = u0;
    *(uint4*)(&ps[r * 72 + seg + 8])  = u1;
    *(uint4*)(&ps[r * 72 + seg + 16]) = u2;
    *(uint4*)(&ps[r * 72 + seg + 24]) = u3;
  }
  // ---- Q B-operand fragments, pre-scaled by SCALE_ (so P = __expf(s) later)
  s16x8 qb[2][2];
  #pragma unroll
  for (int nt = 0; nt < 2; nt++)
    #pragma unroll
    for (int ks_ = 0; ks_ < 2; ks_++) {
      qb[nt][ks_] = *(const s16x8*)(&ps[(w * 32 + nt * 16 + m16) * 72 + ks_ * 32 + quad * 8]);
      unsigned int* u = (unsigned int*)&qb[nt][ks_];
      #pragma unroll
      for (int i = 0; i < 4; i++)
        u[i] = pkbf2(blo(u[i]) * SCALE_, bhi(u[i]) * SCALE_);
    }
  // ones fragment for row-sum MFMA
  s16x8 vone;
  #pragma unroll
  for (int i = 0; i < 8; i++) vone[i] = (short)0x3F80;

  f32x4 oacc[2][4], lacc[2];
  #pragma unroll
  for (int mt = 0; mt < 2; mt++) {
    lacc[mt] = (f32x4){0.f, 0.f, 0.f, 0.f};
    #pragma unroll
    for (int dt = 0; dt < 4; dt++) oacc[mt][dt] = (f32x4){0.f, 0.f, 0.f, 0.f};
  }

  // ---- prefetch addressing
  int kkey = t >> 2, kseg = (t & 3) * 16;
  const unsigned short* kbase = qkv + (size_t)(b * N_) * QKVC_ + D_ + h * 64;
  int vp2 = t & 31, vseg = t >> 5;
  const unsigned short* vbase = qkv + (size_t)(b * N_) * QKVC_ + 2 * D_ + h * 64 + vseg * 8;
  uint4 kr0, kr1, vr0, vr1;
  {
    const uint4* ksrc = (const uint4*)(kbase + (size_t)kkey * QKVC_ + kseg);
    kr0 = ksrc[0]; kr1 = ksrc[1];
    vr0 = *(const uint4*)(vbase + (size_t)(2 * vp2) * QKVC_);
    vr1 = *(const uint4*)(vbase + (size_t)(2 * vp2 + 1) * QKVC_);
  }

  for (int jt = 0; jt < 16; jt++) {
    __syncthreads();  // prior QK(ks)/PV(vs) reads complete
    // ---- write prefetched K tile [key][hd]
    *(uint4*)(&ks[kkey * 72 + kseg])     = kr0;
    *(uint4*)(&ks[kkey * 72 + kseg + 8]) = kr1;
    // ---- write prefetched V^T tile [dim][keypair] (perm pack)
    {
      const unsigned int* vaw = (const unsigned int*)&vr0;
      const unsigned int* vbw = (const unsigned int*)&vr1;
      #pragma unroll
      for (int i = 0; i < 4; i++) {
        vs[(vseg * 8 + 2 * i)     * 36 + vp2] = __builtin_amdgcn_perm(vbw[i], vaw[i], 0x05040100u);
        vs[(vseg * 8 + 2 * i + 1) * 36 + vp2] = __builtin_amdgcn_perm(vbw[i], vaw[i], 0x07060302u);
      }
    }
    __syncthreads();  // staging visible (no global loads in flight here)
    // ---- issue next tile's loads; they overlap QK+exp, drain at next barrier
    if (jt < 15) {
      int j0 = (jt + 1) * 64;
      const uint4* ksrc = (const uint4*)(kbase + (size_t)(j0 + kkey) * QKVC_ + kseg);
      kr0 = ksrc[0]; kr1 = ksrc[1];
      vr0 = *(const uint4*)(vbase + (size_t)(j0 + 2 * vp2) * QKVC_);
      vr1 = *(const uint4*)(vbase + (size_t)(j0 + 2 * vp2 + 1) * QKVC_);
    }
    // ---- QK: S^T[key][qrow] per wave: 4 key-tiles x 2 row-tiles
    f32x4 sacc[4][2];
    #pragma unroll
    for (int kt = 0; kt < 4; kt++) {
      s16x8 ka0 = *(const s16x8*)(&ks[(kt * 16 + m16) * 72 + quad * 8]);
      s16x8 ka1 = *(const s16x8*)(&ks[(kt * 16 + m16) * 72 + 32 + quad * 8]);
      #pragma unroll
      for (int nt = 0; nt < 2; nt++) {
        f32x4 s = (f32x4){0.f, 0.f, 0.f, 0.f};
        s = __builtin_amdgcn_mfma_f32_16x16x32_bf16(ka0, qb[nt][0], s, 0, 0, 0);
        s = __builtin_amdgcn_mfma_f32_16x16x32_bf16(ka1, qb[nt][1], s, 0, 0, 0);
        sacc[kt][nt] = s;
      }
    }
    // ---- P = exp(s) (scale pre-folded); perm-pack 4 keys -> b64 write
    #pragma unroll
    for (int kt = 0; kt < 4; kt++) {
      #pragma unroll
      for (int nt = 0; nt < 2; nt++) {
        f32x4 s = sacc[kt][nt];
        float p0 = __expf(s[0]);
        float p1 = __expf(s[1]);
        float p2 = __expf(s[2]);
        float p3 = __expf(s[3]);
        uint2 pk = {pkbf2(p0, p1), pkbf2(p2, p3)};
        *(uint2*)(&ps[(w * 32 + nt * 16 + m16) * 72 + kt * 16 + quad * 4]) = pk;
      }
    }
    __syncthreads();  // ps visible; prefetch loads drained here (overlapped)
    // ---- PV: O += P·V ; l += P·1 (C-layout row-sums)
    s16x8 pa[2][2];
    #pragma unroll
    for (int mt = 0; mt < 2; mt++)
      #pragma unroll
      for (int ks_ = 0; ks_ < 2; ks_++)
        pa[mt][ks_] = *(const s16x8*)(&ps[(w * 32 + mt * 16 + m16) * 72 + ks_ * 32 + quad * 8]);
    const short* vss = (const short*)vs;
    #pragma unroll
    for (int dt = 0; dt < 4; dt++) {
      s16x8 vb0 = *(const s16x8*)(&vss[(dt * 16 + m16) * 72 + quad * 8]);
      s16x8 vb1 = *(const s16x8*)(&vss[(dt * 16 + m16) * 72 + 32 + quad * 8]);
      #pragma unroll
      for (int mt = 0; mt < 2; mt++) {
        oacc[mt][dt] = __builtin_amdgcn_mfma_f32_16x16x32_bf16(pa[mt][0], vb0, oacc[mt][dt], 0, 0, 0);
        oacc[mt][dt] = __builtin_amdgcn_mfma_f32_16x16x32_bf16(pa[mt][1], vb1, oacc[mt][dt], 0, 0, 0);
      }
    }
    #pragma unroll
    for (int mt = 0; mt < 2; mt++) {
      lacc[mt] = __builtin_amdgcn_mfma_f32_16x16x32_bf16(pa[mt][0], vone, lacc[mt], 0, 0, 0);
      lacc[mt] = __builtin_amdgcn_mfma_f32_16x16x32_bf16(pa[mt][1], vone, lacc[mt], 0, 0, 0);
    }
  }
  // ---- tail: key 1024 (q fragments pre-scaled -> p = expf(d))
  if (t < 64)       tailbuf[t]             = bf2f(qkv[(size_t)(b * N_ + 1024) * QKVC_ + D_     + h * 64 + t]);
  else if (t < 128) tailbuf[64 + (t - 64)] = bf2f(qkv[(size_t)(b * N_ + 1024) * QKVC_ + 2 * D_ + h * 64 + (t - 64)]);
  __syncthreads();
  #pragma unroll
  for (int nt = 0; nt < 2; nt++) {
    float d = 0.f;
    #pragma unroll
    for (int jj = 0; jj < 8; jj++) {
      d += bf2f((unsigned short)qb[nt][0][jj]) * tailbuf[quad * 8 + jj];
      d += bf2f((unsigned short)qb[nt][1][jj]) * tailbuf[32 + quad * 8 + jj];
    }
    d += __shfl_xor(d, 16, 64);
    d += __shfl_xor(d, 32, 64);
    float p = __expf(d);
    if (quad == 0) tailbuf[128 + w * 32 + nt * 16 + m16] = p;
  }
  __syncthreads();
  #pragma unroll
  for (int mt = 0; mt < 2; mt++)
    #pragma unroll
    for (int r = 0; r < 4; r++) {
      float pr = tailbuf[128 + w * 32 + mt * 16 + quad * 4 + r];
      lacc[mt][r] += pr;
      #pragma unroll
      for (int dt = 0; dt < 4; dt++)
        oacc[mt][dt][r] += pr * tailbuf[64 + dt * 16 + m16];
    }
  // ---- normalize + store (O layout: row=quad*4+r+mt*16, dim=dt*16+m16)
  #pragma unroll
  for (int mt = 0; mt < 2; mt++) {
    float rinv[4];
    #pragma unroll
    for (int r = 0; r < 4; r++) rinv[r] = 1.0f / lacc[mt][r];
    #pragma unroll
    for (int dt = 0; dt < 4; dt++) {
      #pragma unroll
      for (int r = 0; r < 4; r++) {
        int grow = b * N_ + qbase + w * 32 + mt * 16 + quad * 4 + r;
        attn_out[(size_t)grow * D_ + h * 64 + dt * 16 + m16] = f2bf(oacc[mt][dt][r] * rinv[r]);
      }
    }
  }
}

// ---------------- launch ----------------
extern "C" void kernel_launch(void* const* d_in, const int* in_sizes, int n_in,
                              void* d_out, int out_size, void* d_ws, size_t ws_size,
                              hipStream_t stream) {
  (void)in_sizes; (void)n_in; (void)out_size; (void)ws_size;
  const float* x     = (const float*)d_in[0];
  const float* canny = (const float*)d_in[1];
  const float* noise = (const float*)d_in[2];
  const float* lnw   = (const float*)d_in[3];
  const float* lnb   = (const float*)d_in[4];
  const float* wqkv  = (const float*)d_in[5];
  const float* wout  = (const float*)d_in[6];
  const float* bout  = (const float*)d_in[7];
  float* out = (float*)d_out;
  char* ws = (char*)d_ws;

  unsigned short* xn    = (unsigned short*)(ws);              // 8320*768 bf16 (reused as attn_out)
  unsigned short* wqkvT = (unsigned short*)(ws + 12779520);   // 2304*768
  unsigned short* woutT = (unsigned short*)(ws + 16318464);   // 768*768
  unsigned short* qkv   = (unsigned short*)(ws + 17498112);   // 8200*2304

  transpose_f2b2<<<dim3(96, 24), 256, 0, stream>>>(wqkv, wqkvT, wout, woutT);
  layernorm_k<<<dim3(ROWS_), 256, 0, stream>>>(x, lnw, lnb, xn);
  gemm_bt<false><<<dim3(QKVC_ / 128, ROWS_PAD_ / 128), 256, 0, stream>>>(
      xn, wqkvT, (void*)qkv, nullptr, ROWS_, QKVC_, D_);
  attn_cls<<<dim3(B_ * H_), 256, 0, stream>>>(qkv, canny, noise, xn);
  attn_main<<<dim3(8 * H_ * B_), 256, 0, stream>>>(qkv, xn);
  gemm_bt<true><<<dim3(D_ / 128, ROWS_PAD_ / 128), 256, 0, stream>>>(
      xn, woutT, (void*)out, bout, ROWS_, D_, D_);
}